// Round 2
// baseline (1310.270 us; speedup 1.0000x reference)
//
#include <hip/hip_runtime.h>
#include <math.h>

#define N_NODES 50000
#define N_EDGES 600000
#define DIM     128
#define NHEAD   8
#define DHEAD   16
#define DFF     512

// ---------- float atomic-max encoding (monotonic uint) ----------
__device__ __forceinline__ unsigned fenc(float f) {
  unsigned u = __float_as_uint(f);
  return (u & 0x80000000u) ? ~u : (u | 0x80000000u);
}
__device__ __forceinline__ float fdec(unsigned e) {
  unsigned u = (e & 0x80000000u) ? (e ^ 0x80000000u) : ~e;
  return __uint_as_float(u);
}

// ---------- K0/K7: cross-ratio from 4 rows of a [*,128] matrix ----------
// mode 0: out[0] = cr           (addone = 0 for raw x)
// mode 1: out[0] = scale from cr0p[0] and cr (addone = 1 for homogeneous coord)
__global__ __launch_bounds__(128) void cr_kernel(const float* __restrict__ x,
                                                 float addone, int mode,
                                                 const float* __restrict__ cr0p,
                                                 float* __restrict__ out) {
  __shared__ float red[4][2];
  const int t = threadIdx.x, lane = t & 63, w = t >> 6;
  float a = x[t], b = x[128 + t], c = x[256 + t], d = x[384 + t];
  float pac = a * c, pbd = b * d, pad = a * d, pbc = b * c;
  #pragma unroll
  for (int off = 32; off; off >>= 1) {
    pac += __shfl_xor(pac, off);
    pbd += __shfl_xor(pbd, off);
    pad += __shfl_xor(pad, off);
    pbc += __shfl_xor(pbc, off);
  }
  if (lane == 0) { red[0][w] = pac; red[1][w] = pbd; red[2][w] = pad; red[3][w] = pbc; }
  __syncthreads();
  if (t == 0) {
    float ac = red[0][0] + red[0][1] + addone;
    float bd = red[1][0] + red[1][1] + addone;
    float ad = red[2][0] + red[2][1] + addone;
    float bc = red[3][0] + red[3][1] + addone;
    float cr = ac * bd / (ad * bc + 1e-8f);
    if (mode == 0) {
      out[0] = cr;
    } else {
      float cr0 = cr0p[0];
      bool fin_cr  = (cr == cr)  && (fabsf(cr)  < __int_as_float(0x7f800000));
      bool fin_cr0 = (cr0 == cr0) && (fabsf(cr0) < __int_as_float(0x7f800000));
      bool valid = fin_cr && fin_cr0 && (fabsf(cr) > 1e-8f);
      float scale = 1.0f;
      if (valid) scale = sqrtf(sqrtf(fabsf(cr0 / cr)));
      out[0] = scale;
    }
  }
}

// ---------- K1: fused QKV GEMM, 32 rows/block, 4x4 micro-tiles ----------
// LDS 80 KB -> 2 blocks/CU. Inner loop: per 16 FMAs, 1 broadcast ds_read_b128
// (xs) + 1 conflict-free ds_read_b128 (wsm) -> compute-bound.
__global__ __launch_bounds__(256) void qkv_kernel(
    const float* __restrict__ x, const float* __restrict__ Wq,
    const float* __restrict__ Wk, const float* __restrict__ Wv,
    float* __restrict__ Qo, float* __restrict__ Ko, float* __restrict__ Vo,
    int nrows) {
  __shared__ float xs[32 * 128];   // 16 KB
  __shared__ float wsm[128 * 128]; // 64 KB
  const int tid = threadIdx.x;
  const int r0g = blockIdx.x * 32;
  for (int i = tid; i < 1024; i += 256) {
    int r = i >> 5, c4 = i & 31;
    float4 v = make_float4(0.f, 0.f, 0.f, 0.f);
    if (r0g + r < nrows) v = ((const float4*)x)[(size_t)(r0g + r) * 32 + c4];
    ((float4*)xs)[i] = v;
  }
  const int ct = tid & 31, rt = tid >> 5;
  for (int w = 0; w < 3; ++w) {
    const float* W = (w == 0) ? Wq : (w == 1) ? Wk : Wv;
    float* O       = (w == 0) ? Qo : (w == 1) ? Ko : Vo;
    __syncthreads();
    for (int i = tid; i < 4096; i += 256)
      ((float4*)wsm)[i] = ((const float4*)W)[i];
    __syncthreads();
    float acc[4][4] = {};
    for (int k = 0; k < 128; k += 4) {
      float4 w0 = ((float4*)wsm)[(k + 0) * 32 + ct];
      float4 w1 = ((float4*)wsm)[(k + 1) * 32 + ct];
      float4 w2 = ((float4*)wsm)[(k + 2) * 32 + ct];
      float4 w3 = ((float4*)wsm)[(k + 3) * 32 + ct];
      #pragma unroll
      for (int i = 0; i < 4; ++i) {
        float4 xv = ((float4*)xs)[(rt * 4 + i) * 32 + (k >> 2)];
        acc[i][0] += xv.x * w0.x + xv.y * w1.x + xv.z * w2.x + xv.w * w3.x;
        acc[i][1] += xv.x * w0.y + xv.y * w1.y + xv.z * w2.y + xv.w * w3.y;
        acc[i][2] += xv.x * w0.z + xv.y * w1.z + xv.z * w2.z + xv.w * w3.z;
        acc[i][3] += xv.x * w0.w + xv.y * w1.w + xv.z * w2.w + xv.w * w3.w;
      }
    }
    #pragma unroll
    for (int i = 0; i < 4; ++i) {
      int r = r0g + rt * 4 + i;
      if (r < nrows)
        ((float4*)O)[(size_t)r * 32 + ct] =
            make_float4(acc[i][0], acc[i][1], acc[i][2], acc[i][3]);
    }
  }
}

// ---------- init m (encoded -inf) and denom (0) ----------
__global__ __launch_bounds__(256) void init_kernel(unsigned* __restrict__ menc,
                                                   float* __restrict__ den, int n) {
  int t = blockIdx.x * 256 + threadIdx.x;
  if (t < n) { menc[t] = 0x007FFFFFu; den[t] = 0.f; }
}

// ---------- zero a float4 buffer ----------
__global__ __launch_bounds__(256) void zero_kernel(float4* __restrict__ p, int n4) {
  int t = blockIdx.x * 256 + threadIdx.x;
  if (t < n4) p[t] = make_float4(0.f, 0.f, 0.f, 0.f);
}

// ---------- K2: per-(edge,head) score + atomic segment max ----------
__global__ __launch_bounds__(256) void score_kernel(
    const int* __restrict__ ei, const float* __restrict__ Q,
    const float* __restrict__ K, float* __restrict__ sc,
    unsigned* __restrict__ menc, int nE) {
  int t = blockIdx.x * 256 + threadIdx.x;
  if (t >= nE * NHEAD) return;
  int e = t >> 3, h = t & 7;
  int src = ei[e], dst = ei[nE + e];
  const float4* qp = (const float4*)(Q + (size_t)dst * DIM + h * DHEAD);
  const float4* kp = (const float4*)(K + (size_t)src * DIM + h * DHEAD);
  float s = 0.f;
  #pragma unroll
  for (int i = 0; i < 4; ++i) {
    float4 q = qp[i], k = kp[i];
    s += q.x * k.x + q.y * k.y + q.z * k.z + q.w * k.w;
  }
  s *= 0.25f;  // 1/sqrt(16)
  sc[t] = s;
  atomicMax(&menc[dst * NHEAD + h], fenc(s));
}

// ---------- K3: ex = exp(s - m[dst]) + atomic segment sum ----------
__global__ __launch_bounds__(256) void exp_kernel(
    const int* __restrict__ ei, float* __restrict__ sc,
    const unsigned* __restrict__ menc, float* __restrict__ den, int nE) {
  int t = blockIdx.x * 256 + threadIdx.x;
  if (t >= nE * NHEAD) return;
  int e = t >> 3, h = t & 7;
  int dst = ei[nE + e];
  float m = fdec(menc[dst * NHEAD + h]);
  float ex = expf(sc[t] - m);
  sc[t] = ex;
  unsafeAtomicAdd(&den[dst * NHEAD + h], ex);
}

// ---------- K4: message scatter, one wave per edge ----------
__global__ __launch_bounds__(256) void msg_kernel(
    const int* __restrict__ ei, const float* __restrict__ ex,
    const float* __restrict__ den, const float* __restrict__ V,
    float* __restrict__ att, int nE) {
  int gw = (blockIdx.x * 256 + threadIdx.x) >> 6;
  int lane = threadIdx.x & 63;
  if (gw >= nE) return;
  int src = ei[gw], dst = ei[nE + gw];
  int h = lane >> 3;
  float alpha = ex[(size_t)gw * NHEAD + h] / (den[dst * NHEAD + h] + 1e-16f);
  float2 v = ((const float2*)(V + (size_t)src * DIM))[lane];
  float* o = att + (size_t)dst * DIM + lane * 2;
  unsafeAtomicAdd(o, alpha * v.x);
  unsafeAtomicAdd(o + 1, alpha * v.y);
}

// ---------- K5/K6b: out = LN((a+b)/2)*g + be, one wave per row ----------
__global__ __launch_bounds__(256) void add_ln_kernel(
    const float* __restrict__ a, const float* __restrict__ b,
    const float* __restrict__ g, const float* __restrict__ be,
    float* __restrict__ out, int nrows) {
  int wave = (blockIdx.x * 256 + threadIdx.x) >> 6;
  int lane = threadIdx.x & 63;
  if (wave >= nrows) return;
  float2 av = ((const float2*)a)[(size_t)wave * 64 + lane];
  float2 bv = ((const float2*)b)[(size_t)wave * 64 + lane];
  float y0 = (av.x + bv.x) * 0.5f, y1 = (av.y + bv.y) * 0.5f;
  float s = y0 + y1;
  #pragma unroll
  for (int off = 32; off; off >>= 1) s += __shfl_xor(s, off);
  float mean = s * (1.0f / 128.0f);
  float d0 = y0 - mean, d1 = y1 - mean;
  float v = d0 * d0 + d1 * d1;
  #pragma unroll
  for (int off = 32; off; off >>= 1) v += __shfl_xor(v, off);
  float rstd = 1.0f / sqrtf(v * (1.0f / 128.0f) + 1e-5f);
  float2 gv = ((const float2*)g)[lane];
  float2 bev = ((const float2*)be)[lane];
  float2 o;
  o.x = gv.x * d0 * rstd + bev.x;
  o.y = gv.y * d1 * rstd + bev.y;
  ((float2*)out)[(size_t)wave * 64 + lane] = o;
}

// ---------- K6: fused FFN (relu(y@W1+b1))@W2+b2, 32 rows/block ----------
// LDS 144 KB -> 1 block/CU (4 waves). Hidden never touches HBM (~200 MB saved).
__global__ __launch_bounds__(256) void ffn_kernel(
    const float* __restrict__ y, const float* __restrict__ W1,
    const float* __restrict__ b1, const float* __restrict__ W2,
    const float* __restrict__ b2, float* __restrict__ ff, int nrows) {
  __shared__ float ys[32 * 128];  // 16 KB
  __shared__ float hs[32 * 512];  // 64 KB
  __shared__ float wb[128 * 128]; // 64 KB
  const int tid = threadIdx.x;
  const int r0g = blockIdx.x * 32;
  for (int i = tid; i < 1024; i += 256) {
    int r = i >> 5, c4 = i & 31;
    float4 v = make_float4(0.f, 0.f, 0.f, 0.f);
    if (r0g + r < nrows) v = ((const float4*)y)[(size_t)(r0g + r) * 32 + c4];
    ((float4*)ys)[i] = v;
  }
  const int ct = tid & 31, rt = tid >> 5;
  // hidden = relu(y @ W1 + b1), 4 column chunks of 128
  for (int cc = 0; cc < 4; ++cc) {
    __syncthreads();
    for (int i = tid; i < 4096; i += 256) {
      int k = i >> 5, c4 = i & 31;
      ((float4*)wb)[i] = ((const float4*)W1)[(size_t)k * 128 + cc * 32 + c4];
    }
    __syncthreads();
    float acc[4][4] = {};
    for (int k = 0; k < 128; k += 4) {
      float4 w0 = ((float4*)wb)[(k + 0) * 32 + ct];
      float4 w1 = ((float4*)wb)[(k + 1) * 32 + ct];
      float4 w2 = ((float4*)wb)[(k + 2) * 32 + ct];
      float4 w3 = ((float4*)wb)[(k + 3) * 32 + ct];
      #pragma unroll
      for (int i = 0; i < 4; ++i) {
        float4 xv = ((float4*)ys)[(rt * 4 + i) * 32 + (k >> 2)];
        acc[i][0] += xv.x * w0.x + xv.y * w1.x + xv.z * w2.x + xv.w * w3.x;
        acc[i][1] += xv.x * w0.y + xv.y * w1.y + xv.z * w2.y + xv.w * w3.y;
        acc[i][2] += xv.x * w0.z + xv.y * w1.z + xv.z * w2.z + xv.w * w3.z;
        acc[i][3] += xv.x * w0.w + xv.y * w1.w + xv.z * w2.w + xv.w * w3.w;
      }
    }
    float4 bv = ((const float4*)b1)[cc * 32 + ct];
    #pragma unroll
    for (int i = 0; i < 4; ++i) {
      float4 hv;
      hv.x = fmaxf(acc[i][0] + bv.x, 0.f);
      hv.y = fmaxf(acc[i][1] + bv.y, 0.f);
      hv.z = fmaxf(acc[i][2] + bv.z, 0.f);
      hv.w = fmaxf(acc[i][3] + bv.w, 0.f);
      ((float4*)hs)[(rt * 4 + i) * 128 + cc * 32 + ct] = hv;
    }
  }
  // out = hidden @ W2 + b2, 4 k-chunks of 128
  float acc[4][4] = {};
  for (int kc = 0; kc < 4; ++kc) {
    __syncthreads();
    for (int i = tid; i < 4096; i += 256)
      ((float4*)wb)[i] = ((const float4*)W2)[(size_t)kc * 4096 + i];
    __syncthreads();
    for (int k = 0; k < 128; k += 4) {
      float4 w0 = ((float4*)wb)[(k + 0) * 32 + ct];
      float4 w1 = ((float4*)wb)[(k + 1) * 32 + ct];
      float4 w2 = ((float4*)wb)[(k + 2) * 32 + ct];
      float4 w3 = ((float4*)wb)[(k + 3) * 32 + ct];
      #pragma unroll
      for (int i = 0; i < 4; ++i) {
        float4 hv = ((float4*)hs)[(rt * 4 + i) * 128 + kc * 32 + (k >> 2)];
        acc[i][0] += hv.x * w0.x + hv.y * w1.x + hv.z * w2.x + hv.w * w3.x;
        acc[i][1] += hv.x * w0.y + hv.y * w1.y + hv.z * w2.y + hv.w * w3.y;
        acc[i][2] += hv.x * w0.z + hv.y * w1.z + hv.z * w2.z + hv.w * w3.z;
        acc[i][3] += hv.x * w0.w + hv.y * w1.w + hv.z * w2.w + hv.w * w3.w;
      }
    }
  }
  float4 bv = ((const float4*)b2)[ct];
  #pragma unroll
  for (int i = 0; i < 4; ++i) {
    int r = r0g + rt * 4 + i;
    if (r < nrows)
      ((float4*)ff)[(size_t)r * 32 + ct] =
          make_float4(acc[i][0] + bv.x, acc[i][1] + bv.y,
                      acc[i][2] + bv.z, acc[i][3] + bv.w);
  }
}

// ---------- K8: in-place scale of output ----------
__global__ __launch_bounds__(256) void scale_kernel(float4* __restrict__ out,
                                                    const float* __restrict__ scl,
                                                    int n4) {
  int t = blockIdx.x * 256 + threadIdx.x;
  if (t < n4) {
    float s = scl[0];
    float4 v = out[t];
    v.x *= s; v.y *= s; v.z *= s; v.w *= s;
    out[t] = v;
  }
}

extern "C" void kernel_launch(void* const* d_in, const int* in_sizes, int n_in,
                              void* d_out, int out_size, void* d_ws, size_t ws_size,
                              hipStream_t stream) {
  const float* x   = (const float*)d_in[0];
  const int*   ei  = (const int*)  d_in[1];
  const float* Wq  = (const float*)d_in[2];
  const float* Wk  = (const float*)d_in[3];
  const float* Wv  = (const float*)d_in[4];
  const float* W1  = (const float*)d_in[5];
  const float* b1  = (const float*)d_in[6];
  const float* W2  = (const float*)d_in[7];
  const float* b2  = (const float*)d_in[8];
  const float* g1  = (const float*)d_in[9];
  const float* be1 = (const float*)d_in[10];
  const float* g2  = (const float*)d_in[11];
  const float* be2 = (const float*)d_in[12];
  float* out = (float*)d_out;
  float* ws  = (float*)d_ws;

  const size_t ND  = (size_t)N_NODES * DIM;   // 6,400,000
  const size_t EH  = (size_t)N_EDGES * NHEAD; // 4,800,000
  const size_t NH8 = (size_t)N_NODES * NHEAD; //   400,000

  float*    CR0 = ws;       // ws[0]
  float*    SCL = ws + 1;   // ws[1]
  float*    Q   = ws + 16;
  float*    K   = Q + ND;
  float*    V   = K + ND;
  float*    SC  = V + ND;
  unsigned* M   = (unsigned*)(SC + EH);
  float*    DEN = (float*)M + NH8;
  float*    ATT = Q;  // alias: Q dead after score_kernel
  float*    Y   = K;  // alias: K dead after score_kernel
  float*    FF  = V;  // alias: V dead after msg_kernel
  // total ws use: 16 + 3*ND + EH + 2*NH8 floats ~= 99.2 MB

  // 1. cr0 from raw x rows 0..3
  cr_kernel<<<1, 128, 0, stream>>>(x, 0.0f, 0, nullptr, CR0);
  // 2. Q,K,V GEMMs
  qkv_kernel<<<(N_NODES + 31) / 32, 256, 0, stream>>>(x, Wq, Wk, Wv, Q, K, V, N_NODES);
  // 3. init segment max/sum
  init_kernel<<<(int)((NH8 + 255) / 256), 256, 0, stream>>>(M, DEN, (int)NH8);
  // 4. scores + segment max
  score_kernel<<<(int)(EH / 256), 256, 0, stream>>>(ei, Q, K, SC, M, N_EDGES);
  // 5. exp + segment sum
  exp_kernel<<<(int)(EH / 256), 256, 0, stream>>>(ei, SC, M, DEN, N_EDGES);
  // 6. zero attention accumulator (aliases Q, now dead)
  zero_kernel<<<(int)(ND / 4 / 256), 256, 0, stream>>>((float4*)ATT, (int)(ND / 4));
  // 7. message scatter
  msg_kernel<<<N_EDGES / 4, 256, 0, stream>>>(ei, SC, DEN, V, ATT, N_EDGES);
  // 8. y = LN1((x+att)/2)
  add_ln_kernel<<<N_NODES / 4, 256, 0, stream>>>(x, ATT, g1, be1, Y, N_NODES);
  // 9. ff = FFN(y)
  ffn_kernel<<<(N_NODES + 31) / 32, 256, 0, stream>>>(Y, W1, b1, W2, b2, FF, N_NODES);
  // 10. z = LN2((y+ff)/2) -> d_out
  add_ln_kernel<<<N_NODES / 4, 256, 0, stream>>>(Y, FF, g2, be2, out, N_NODES);
  // 11. cr on z (homogeneous coord adds +1 to each dot), scale factor -> SCL
  cr_kernel<<<1, 128, 0, stream>>>(out, 1.0f, 1, CR0, SCL);
  // 12. out *= scale
  scale_kernel<<<(int)(ND / 4 / 256), 256, 0, stream>>>((float4*)out, SCL, (int)(ND / 4));
}

// Round 3
// 998.742 us; speedup vs baseline: 1.3119x; 1.3119x over previous
//
#include <hip/hip_runtime.h>
#include <hip/hip_bf16.h>
#include <math.h>

#define N_NODES 50000
#define N_EDGES 600000
#define DIM     128
#define NHEAD   8
#define DHEAD   16
#define DFF     512

typedef __attribute__((ext_vector_type(8))) short short8;
typedef __attribute__((ext_vector_type(4))) float f32x4;

__device__ __forceinline__ short f2bf(float f) {
  __hip_bfloat16 h = __float2bfloat16(f);
  union { __hip_bfloat16 h; short s; } u; u.h = h; return u.s;
}

// ---------- float atomic-max encoding (monotonic uint) ----------
__device__ __forceinline__ unsigned fenc(float f) {
  unsigned u = __float_as_uint(f);
  return (u & 0x80000000u) ? ~u : (u | 0x80000000u);
}
__device__ __forceinline__ float fdec(unsigned e) {
  unsigned u = (e & 0x80000000u) ? (e ^ 0x80000000u) : ~e;
  return __uint_as_float(u);
}

// ---------- K0/K7: cross-ratio from 4 rows of a [*,128] matrix ----------
__global__ __launch_bounds__(128) void cr_kernel(const float* __restrict__ x,
                                                 float addone, int mode,
                                                 const float* __restrict__ cr0p,
                                                 float* __restrict__ out) {
  __shared__ float red[4][2];
  const int t = threadIdx.x, lane = t & 63, w = t >> 6;
  float a = x[t], b = x[128 + t], c = x[256 + t], d = x[384 + t];
  float pac = a * c, pbd = b * d, pad = a * d, pbc = b * c;
  #pragma unroll
  for (int off = 32; off; off >>= 1) {
    pac += __shfl_xor(pac, off);
    pbd += __shfl_xor(pbd, off);
    pad += __shfl_xor(pad, off);
    pbc += __shfl_xor(pbc, off);
  }
  if (lane == 0) { red[0][w] = pac; red[1][w] = pbd; red[2][w] = pad; red[3][w] = pbc; }
  __syncthreads();
  if (t == 0) {
    float ac = red[0][0] + red[0][1] + addone;
    float bd = red[1][0] + red[1][1] + addone;
    float ad = red[2][0] + red[2][1] + addone;
    float bc = red[3][0] + red[3][1] + addone;
    float cr = ac * bd / (ad * bc + 1e-8f);
    if (mode == 0) {
      out[0] = cr;
    } else {
      float cr0 = cr0p[0];
      bool fin_cr  = (cr == cr)  && (fabsf(cr)  < __int_as_float(0x7f800000));
      bool fin_cr0 = (cr0 == cr0) && (fabsf(cr0) < __int_as_float(0x7f800000));
      bool valid = fin_cr && fin_cr0 && (fabsf(cr) > 1e-8f);
      float scale = 1.0f;
      if (valid) scale = sqrtf(sqrtf(fabsf(cr0 / cr)));
      out[0] = scale;
    }
  }
}

// ---------- K1: fused QKV GEMM, f32 (unchanged this round) ----------
__global__ __launch_bounds__(256) void qkv_kernel(
    const float* __restrict__ x, const float* __restrict__ Wq,
    const float* __restrict__ Wk, const float* __restrict__ Wv,
    float* __restrict__ Qo, float* __restrict__ Ko, float* __restrict__ Vo,
    int nrows) {
  __shared__ float xs[32 * 128];   // 16 KB
  __shared__ float wsm[128 * 128]; // 64 KB
  const int tid = threadIdx.x;
  const int r0g = blockIdx.x * 32;
  for (int i = tid; i < 1024; i += 256) {
    int r = i >> 5, c4 = i & 31;
    float4 v = make_float4(0.f, 0.f, 0.f, 0.f);
    if (r0g + r < nrows) v = ((const float4*)x)[(size_t)(r0g + r) * 32 + c4];
    ((float4*)xs)[i] = v;
  }
  const int ct = tid & 31, rt = tid >> 5;
  for (int w = 0; w < 3; ++w) {
    const float* W = (w == 0) ? Wq : (w == 1) ? Wk : Wv;
    float* O       = (w == 0) ? Qo : (w == 1) ? Ko : Vo;
    __syncthreads();
    for (int i = tid; i < 4096; i += 256)
      ((float4*)wsm)[i] = ((const float4*)W)[i];
    __syncthreads();
    float acc[4][4] = {};
    for (int k = 0; k < 128; k += 4) {
      float4 w0 = ((float4*)wsm)[(k + 0) * 32 + ct];
      float4 w1 = ((float4*)wsm)[(k + 1) * 32 + ct];
      float4 w2 = ((float4*)wsm)[(k + 2) * 32 + ct];
      float4 w3 = ((float4*)wsm)[(k + 3) * 32 + ct];
      #pragma unroll
      for (int i = 0; i < 4; ++i) {
        float4 xv = ((float4*)xs)[(rt * 4 + i) * 32 + (k >> 2)];
        acc[i][0] += xv.x * w0.x + xv.y * w1.x + xv.z * w2.x + xv.w * w3.x;
        acc[i][1] += xv.x * w0.y + xv.y * w1.y + xv.z * w2.y + xv.w * w3.y;
        acc[i][2] += xv.x * w0.z + xv.y * w1.z + xv.z * w2.z + xv.w * w3.z;
        acc[i][3] += xv.x * w0.w + xv.y * w1.w + xv.z * w2.w + xv.w * w3.w;
      }
    }
    #pragma unroll
    for (int i = 0; i < 4; ++i) {
      int r = r0g + rt * 4 + i;
      if (r < nrows)
        ((float4*)O)[(size_t)r * 32 + ct] =
            make_float4(acc[i][0], acc[i][1], acc[i][2], acc[i][3]);
    }
  }
}

// ---------- weight transpose + bf16 convert: W1T[512][128], W2T[128][512] ----------
__global__ __launch_bounds__(256) void convw_kernel(
    const float* __restrict__ W1, const float* __restrict__ W2,
    short* __restrict__ W1T, short* __restrict__ W2T) {
  int t = blockIdx.x * 256 + threadIdx.x;
  if (t < 512 * 128) {
    int n = t >> 7, k = t & 127;               // W1T[n][k] = W1[k][n]
    W1T[t] = f2bf(W1[(size_t)k * 512 + n]);
  } else {
    int i = t - 512 * 128;
    int n = i >> 9, k = i & 511;               // W2T[n][k] = W2[k][n]
    W2T[i] = f2bf(W2[(size_t)k * 128 + n]);
  }
}

// ---------- init m (encoded -inf) and denom (0) ----------
__global__ __launch_bounds__(256) void init_kernel(unsigned* __restrict__ menc,
                                                   float* __restrict__ den, int n) {
  int t = blockIdx.x * 256 + threadIdx.x;
  if (t < n) { menc[t] = 0x007FFFFFu; den[t] = 0.f; }
}

// ---------- zero a float4 buffer ----------
__global__ __launch_bounds__(256) void zero_kernel(float4* __restrict__ p, int n4) {
  int t = blockIdx.x * 256 + threadIdx.x;
  if (t < n4) p[t] = make_float4(0.f, 0.f, 0.f, 0.f);
}

// ---------- K2: per-(edge,head) score + atomic segment max ----------
__global__ __launch_bounds__(256) void score_kernel(
    const int* __restrict__ ei, const float* __restrict__ Q,
    const float* __restrict__ K, float* __restrict__ sc,
    unsigned* __restrict__ menc, int nE) {
  int t = blockIdx.x * 256 + threadIdx.x;
  if (t >= nE * NHEAD) return;
  int e = t >> 3, h = t & 7;
  int src = ei[e], dst = ei[nE + e];
  const float4* qp = (const float4*)(Q + (size_t)dst * DIM + h * DHEAD);
  const float4* kp = (const float4*)(K + (size_t)src * DIM + h * DHEAD);
  float s = 0.f;
  #pragma unroll
  for (int i = 0; i < 4; ++i) {
    float4 q = qp[i], k = kp[i];
    s += q.x * k.x + q.y * k.y + q.z * k.z + q.w * k.w;
  }
  s *= 0.25f;  // 1/sqrt(16)
  sc[t] = s;
  atomicMax(&menc[dst * NHEAD + h], fenc(s));
}

// ---------- K3: ex = exp(s - m[dst]) + atomic segment sum ----------
__global__ __launch_bounds__(256) void exp_kernel(
    const int* __restrict__ ei, float* __restrict__ sc,
    const unsigned* __restrict__ menc, float* __restrict__ den, int nE) {
  int t = blockIdx.x * 256 + threadIdx.x;
  if (t >= nE * NHEAD) return;
  int e = t >> 3, h = t & 7;
  int dst = ei[nE + e];
  float m = fdec(menc[dst * NHEAD + h]);
  float ex = expf(sc[t] - m);
  sc[t] = ex;
  unsafeAtomicAdd(&den[dst * NHEAD + h], ex);
}

// ---------- K4: message scatter, one wave per edge ----------
__global__ __launch_bounds__(256) void msg_kernel(
    const int* __restrict__ ei, const float* __restrict__ ex,
    const float* __restrict__ den, const float* __restrict__ V,
    float* __restrict__ att, int nE) {
  int gw = (blockIdx.x * 256 + threadIdx.x) >> 6;
  int lane = threadIdx.x & 63;
  if (gw >= nE) return;
  int src = ei[gw], dst = ei[nE + gw];
  int h = lane >> 3;
  float alpha = ex[(size_t)gw * NHEAD + h] / (den[dst * NHEAD + h] + 1e-16f);
  float2 v = ((const float2*)(V + (size_t)src * DIM))[lane];
  float* o = att + (size_t)dst * DIM + lane * 2;
  unsafeAtomicAdd(o, alpha * v.x);
  unsafeAtomicAdd(o + 1, alpha * v.y);
}

// ---------- K5/K6b: out = LN((a+b)/2)*g + be (+ optional bf16 copy) ----------
__global__ __launch_bounds__(256) void add_ln_kernel(
    const float* __restrict__ a, const float* __restrict__ b,
    const float* __restrict__ g, const float* __restrict__ be,
    float* __restrict__ out, short* __restrict__ ybf, int nrows) {
  int wave = (blockIdx.x * 256 + threadIdx.x) >> 6;
  int lane = threadIdx.x & 63;
  if (wave >= nrows) return;
  float2 av = ((const float2*)a)[(size_t)wave * 64 + lane];
  float2 bv = ((const float2*)b)[(size_t)wave * 64 + lane];
  float y0 = (av.x + bv.x) * 0.5f, y1 = (av.y + bv.y) * 0.5f;
  float s = y0 + y1;
  #pragma unroll
  for (int off = 32; off; off >>= 1) s += __shfl_xor(s, off);
  float mean = s * (1.0f / 128.0f);
  float d0 = y0 - mean, d1 = y1 - mean;
  float v = d0 * d0 + d1 * d1;
  #pragma unroll
  for (int off = 32; off; off >>= 1) v += __shfl_xor(v, off);
  float rstd = 1.0f / sqrtf(v * (1.0f / 128.0f) + 1e-5f);
  float2 gv = ((const float2*)g)[lane];
  float2 bev = ((const float2*)be)[lane];
  float2 o;
  o.x = gv.x * d0 * rstd + bev.x;
  o.y = gv.y * d1 * rstd + bev.y;
  ((float2*)out)[(size_t)wave * 64 + lane] = o;
  if (ybf) {
    unsigned pk = (unsigned short)f2bf(o.x) | ((unsigned)(unsigned short)f2bf(o.y) << 16);
    ((unsigned*)ybf)[(size_t)wave * 64 + lane] = pk;
  }
}

// ---------- K6: bf16-MFMA fused FFN ----------
// 64 rows/block, 4 waves, 16 rows/wave. Y rows persist in registers as A-frags.
// Per 32-wide hidden chunk: GEMM1 (8 mfma) -> bias/relu -> per-wave LDS
// round-trip (f32, stride 40 => bank-uniform b128 reads) -> A-frag -> GEMM2
// (8 mfma) into persistent 128-wide f32 accumulator. LDS = 10 KB total.
// MFMA layouts (gfx950 16x16x32_bf16): A: row=l&15, k=(l>>4)*8+j;
// B: col=l&15, k=(l>>4)*8+j; D: col=l&15, row=(l>>4)*4+reg  [m89/m91].
__global__ __launch_bounds__(256) void ffn_mfma_kernel(
    const short* __restrict__ Ybf, const short* __restrict__ W1T,
    const float* __restrict__ b1, const short* __restrict__ W2T,
    const float* __restrict__ b2, float* __restrict__ ff, int nrows) {
  __shared__ float Hlds[4 * 16 * 40];  // 10240 B, per-wave 16x40 region
  const int tid = threadIdx.x;
  const int w = tid >> 6, lane = tid & 63;
  const int a = lane >> 4, c = lane & 15;
  const int rowbase = blockIdx.x * 64 + w * 16;
  float* Hw = Hlds + w * (16 * 40);

  short8 af[4];
  {
    int r = rowbase + c;  // A row (N_NODES % 16 == 0 => whole wave valid/invalid)
    if (r < nrows) {
      const short* yp = Ybf + (size_t)r * 128 + a * 8;
      #pragma unroll
      for (int kc = 0; kc < 4; ++kc)
        af[kc] = *(const short8*)(yp + kc * 32);
    } else {
      short8 z = {0, 0, 0, 0, 0, 0, 0, 0};
      #pragma unroll
      for (int kc = 0; kc < 4; ++kc) af[kc] = z;
    }
  }

  f32x4 acc2[8];
  #pragma unroll
  for (int i = 0; i < 8; ++i) acc2[i] = (f32x4){0.f, 0.f, 0.f, 0.f};

  for (int hc = 0; hc < 16; ++hc) {
    f32x4 acc1[2];
    acc1[0] = (f32x4){0.f, 0.f, 0.f, 0.f};
    acc1[1] = (f32x4){0.f, 0.f, 0.f, 0.f};
    #pragma unroll
    for (int t = 0; t < 2; ++t) {
      const short* wp = W1T + (size_t)(hc * 32 + t * 16 + c) * 128 + a * 8;
      #pragma unroll
      for (int kc = 0; kc < 4; ++kc) {
        short8 bfr = *(const short8*)(wp + kc * 32);
        acc1[t] = __builtin_amdgcn_mfma_f32_16x16x32_bf16(af[kc], bfr, acc1[t], 0, 0, 0);
      }
    }
    // bias + relu, stash H chunk (rows = 4a+r, cols = t*16+c) in wave LDS
    #pragma unroll
    for (int t = 0; t < 2; ++t) {
      float b1v = b1[hc * 32 + t * 16 + c];
      #pragma unroll
      for (int r = 0; r < 4; ++r) {
        float hv = fmaxf(acc1[t][r] + b1v, 0.f);
        Hw[(4 * a + r) * 40 + t * 16 + c] = hv;
      }
    }
    __syncthreads();  // cross-lane RAW inside wave; barrier = safe vs compiler reordering
    float4 h0 = *(const float4*)(Hw + c * 40 + a * 8);
    float4 h1 = *(const float4*)(Hw + c * 40 + a * 8 + 4);
    short8 a2;
    a2[0] = f2bf(h0.x); a2[1] = f2bf(h0.y); a2[2] = f2bf(h0.z); a2[3] = f2bf(h0.w);
    a2[4] = f2bf(h1.x); a2[5] = f2bf(h1.y); a2[6] = f2bf(h1.z); a2[7] = f2bf(h1.w);
    __syncthreads();  // WAR guard before next chunk's writes
    #pragma unroll
    for (int nt = 0; nt < 8; ++nt) {
      const short* wp = W2T + (size_t)(nt * 16 + c) * 512 + hc * 32 + a * 8;
      short8 bfr = *(const short8*)wp;
      acc2[nt] = __builtin_amdgcn_mfma_f32_16x16x32_bf16(a2, bfr, acc2[nt], 0, 0, 0);
    }
  }
  #pragma unroll
  for (int nt = 0; nt < 8; ++nt) {
    float b2v = b2[nt * 16 + c];
    #pragma unroll
    for (int r = 0; r < 4; ++r) {
      int row = rowbase + 4 * a + r;
      if (row < nrows)
        ff[(size_t)row * 128 + nt * 16 + c] = acc2[nt][r] + b2v;
    }
  }
}

// ---------- K8: in-place scale of output ----------
__global__ __launch_bounds__(256) void scale_kernel(float4* __restrict__ out,
                                                    const float* __restrict__ scl,
                                                    int n4) {
  int t = blockIdx.x * 256 + threadIdx.x;
  if (t < n4) {
    float s = scl[0];
    float4 v = out[t];
    v.x *= s; v.y *= s; v.z *= s; v.w *= s;
    out[t] = v;
  }
}

extern "C" void kernel_launch(void* const* d_in, const int* in_sizes, int n_in,
                              void* d_out, int out_size, void* d_ws, size_t ws_size,
                              hipStream_t stream) {
  const float* x   = (const float*)d_in[0];
  const int*   ei  = (const int*)  d_in[1];
  const float* Wq  = (const float*)d_in[2];
  const float* Wk  = (const float*)d_in[3];
  const float* Wv  = (const float*)d_in[4];
  const float* W1  = (const float*)d_in[5];
  const float* b1  = (const float*)d_in[6];
  const float* W2  = (const float*)d_in[7];
  const float* b2  = (const float*)d_in[8];
  const float* g1  = (const float*)d_in[9];
  const float* be1 = (const float*)d_in[10];
  const float* g2  = (const float*)d_in[11];
  const float* be2 = (const float*)d_in[12];
  float* out = (float*)d_out;
  float* ws  = (float*)d_ws;

  const size_t ND  = (size_t)N_NODES * DIM;   // 6,400,000
  const size_t EH  = (size_t)N_EDGES * NHEAD; // 4,800,000
  const size_t NH8 = (size_t)N_NODES * NHEAD; //   400,000

  float*    CR0 = ws;       // ws[0]
  float*    SCL = ws + 1;   // ws[1]
  float*    Q   = ws + 16;
  float*    K   = Q + ND;
  float*    V   = K + ND;
  float*    SC  = V + ND;
  unsigned* M   = (unsigned*)(SC + EH);
  float*    DEN = (float*)M + NH8;
  short*    W1T = (short*)(DEN + NH8);        // 512*128 bf16
  short*    W2T = W1T + 512 * 128;            // 128*512 bf16
  short*    YBF = W2T + 512 * 128;            // 50000*128 bf16
  float*    ATT = Q;  // alias: Q dead after score_kernel
  float*    Y   = K;  // alias: K dead after score_kernel
  float*    FF  = V;  // alias: V dead after msg_kernel
  // total ws use ~= 99.2 MB + 13.1 MB bf16 buffers

  // 0. weight transpose->bf16 (tiny)
  convw_kernel<<<512, 256, 0, stream>>>(W1, W2, W1T, W2T);
  // 1. cr0 from raw x rows 0..3
  cr_kernel<<<1, 128, 0, stream>>>(x, 0.0f, 0, nullptr, CR0);
  // 2. Q,K,V GEMMs
  qkv_kernel<<<(N_NODES + 31) / 32, 256, 0, stream>>>(x, Wq, Wk, Wv, Q, K, V, N_NODES);
  // 3. init segment max/sum
  init_kernel<<<(int)((NH8 + 255) / 256), 256, 0, stream>>>(M, DEN, (int)NH8);
  // 4. scores + segment max
  score_kernel<<<(int)(EH / 256), 256, 0, stream>>>(ei, Q, K, SC, M, N_EDGES);
  // 5. exp + segment sum
  exp_kernel<<<(int)(EH / 256), 256, 0, stream>>>(ei, SC, M, DEN, N_EDGES);
  // 6. zero attention accumulator (aliases Q, now dead)
  zero_kernel<<<(int)(ND / 4 / 256), 256, 0, stream>>>((float4*)ATT, (int)(ND / 4));
  // 7. message scatter
  msg_kernel<<<N_EDGES / 4, 256, 0, stream>>>(ei, SC, DEN, V, ATT, N_EDGES);
  // 8. y = LN1((x+att)/2)  (+ bf16 copy for FFN)
  add_ln_kernel<<<N_NODES / 4, 256, 0, stream>>>(x, ATT, g1, be1, Y, YBF, N_NODES);
  // 9. ff = FFN(y)  — bf16 MFMA
  ffn_mfma_kernel<<<(N_NODES + 63) / 64, 256, 0, stream>>>(YBF, W1T, b1, W2T, b2, FF, N_NODES);
  // 10. z = LN2((y+ff)/2) -> d_out
  add_ln_kernel<<<N_NODES / 4, 256, 0, stream>>>(Y, FF, g2, be2, out, nullptr, N_NODES);
  // 11. cr on z, scale factor -> SCL
  cr_kernel<<<1, 128, 0, stream>>>(out, 1.0f, 1, CR0, SCL);
  // 12. out *= scale
  scale_kernel<<<(int)(ND / 4 / 256), 256, 0, stream>>>((float4*)out, SCL, (int)(ND / 4));
}

// Round 9
// 551.306 us; speedup vs baseline: 2.3767x; 1.8116x over previous
//
#include <hip/hip_runtime.h>
#include <hip/hip_bf16.h>
#include <math.h>

#define N_NODES 50000
#define N_EDGES 600000
#define DIM     128
#define NHEAD   8
#define DHEAD   16
#define DFF     512

typedef __attribute__((ext_vector_type(8))) short short8;
typedef __attribute__((ext_vector_type(4))) float f32x4;

__device__ __forceinline__ short f2bf(float f) {
  __hip_bfloat16 h = __float2bfloat16(f);
  union { __hip_bfloat16 h; short s; } u; u.h = h; return u.s;
}

// ---------- K0/K7: cross-ratio from 4 rows of a [*,128] matrix ----------
__global__ __launch_bounds__(128) void cr_kernel(const float* __restrict__ x,
                                                 float addone, int mode,
                                                 const float* __restrict__ cr0p,
                                                 float* __restrict__ out) {
  __shared__ float red[4][2];
  const int t = threadIdx.x, lane = t & 63, w = t >> 6;
  float a = x[t], b = x[128 + t], c = x[256 + t], d = x[384 + t];
  float pac = a * c, pbd = b * d, pad = a * d, pbc = b * c;
  #pragma unroll
  for (int off = 32; off; off >>= 1) {
    pac += __shfl_xor(pac, off);
    pbd += __shfl_xor(pbd, off);
    pad += __shfl_xor(pad, off);
    pbc += __shfl_xor(pbc, off);
  }
  if (lane == 0) { red[0][w] = pac; red[1][w] = pbd; red[2][w] = pad; red[3][w] = pbc; }
  __syncthreads();
  if (t == 0) {
    float ac = red[0][0] + red[0][1] + addone;
    float bd = red[1][0] + red[1][1] + addone;
    float ad = red[2][0] + red[2][1] + addone;
    float bc = red[3][0] + red[3][1] + addone;
    float cr = ac * bd / (ad * bc + 1e-8f);
    if (mode == 0) {
      out[0] = cr;
    } else {
      float cr0 = cr0p[0];
      bool fin_cr  = (cr == cr)  && (fabsf(cr)  < __int_as_float(0x7f800000));
      bool fin_cr0 = (cr0 == cr0) && (fabsf(cr0) < __int_as_float(0x7f800000));
      bool valid = fin_cr && fin_cr0 && (fabsf(cr) > 1e-8f);
      float scale = 1.0f;
      if (valid) scale = sqrtf(sqrtf(fabsf(cr0 / cr)));
      out[0] = scale;
    }
  }
}

// ---------- weight transpose + bf16 convert: W1T[512][128], W2T[128][512] ----------
__global__ __launch_bounds__(256) void convw_kernel(
    const float* __restrict__ W1, const float* __restrict__ W2,
    short* __restrict__ W1T, short* __restrict__ W2T) {
  int t = blockIdx.x * 256 + threadIdx.x;
  if (t < 512 * 128) {
    int n = t >> 7, k = t & 127;               // W1T[n][k] = W1[k][n]
    W1T[t] = f2bf(W1[(size_t)k * 512 + n]);
  } else {
    int i = t - 512 * 128;
    int n = i >> 9, k = i & 511;               // W2T[n][k] = W2[k][n]
    W2T[i] = f2bf(W2[(size_t)k * 128 + n]);
  }
}

// ---------- Wq/Wk/Wv transpose + bf16 convert: each [128][128] ----------
__global__ __launch_bounds__(256) void convqkv_kernel(
    const float* __restrict__ Wq, const float* __restrict__ Wk,
    const float* __restrict__ Wv, short* __restrict__ WqT,
    short* __restrict__ WkT, short* __restrict__ WvT) {
  int t = blockIdx.x * 256 + threadIdx.x;  // 0..49151
  int m = t >> 14, i = t & 16383;
  int n = i >> 7, k = i & 127;             // WT[n][k] = W[k][n]
  const float* W = (m == 0) ? Wq : (m == 1) ? Wk : Wv;
  short*      WT = (m == 0) ? WqT : (m == 1) ? WkT : WvT;
  WT[i] = f2bf(W[(size_t)k * 128 + n]);
}

// ---------- K1: bf16-MFMA QKV GEMM ----------
// 64 rows/block, 4 waves x 16 rows. Same fragment addressing as ffn_mfma
// (HW-validated in R3). x rows converted f32->bf16 in-register at load.
__global__ __launch_bounds__(256) void qkv_mfma_kernel(
    const float* __restrict__ x, const short* __restrict__ WqT,
    const short* __restrict__ WkT, const short* __restrict__ WvT,
    float* __restrict__ Qo, float* __restrict__ Ko, float* __restrict__ Vo,
    int nrows) {
  const int tid = threadIdx.x;
  const int w = tid >> 6, lane = tid & 63;
  const int a = lane >> 4, c = lane & 15;
  const int rowbase = blockIdx.x * 64 + w * 16;

  short8 af[4];
  {
    int r = rowbase + c;  // A: row = lane&15, k = (lane>>4)*8 + j (+32*kc)
    if (r < nrows) {
      const float* xp = x + (size_t)r * 128 + a * 8;
      #pragma unroll
      for (int kc = 0; kc < 4; ++kc) {
        float4 x0 = *(const float4*)(xp + kc * 32);
        float4 x1 = *(const float4*)(xp + kc * 32 + 4);
        short8 v;
        v[0] = f2bf(x0.x); v[1] = f2bf(x0.y); v[2] = f2bf(x0.z); v[3] = f2bf(x0.w);
        v[4] = f2bf(x1.x); v[5] = f2bf(x1.y); v[6] = f2bf(x1.z); v[7] = f2bf(x1.w);
        af[kc] = v;
      }
    } else {
      short8 z = {0, 0, 0, 0, 0, 0, 0, 0};
      #pragma unroll
      for (int kc = 0; kc < 4; ++kc) af[kc] = z;
    }
  }

  #pragma unroll
  for (int m = 0; m < 3; ++m) {
    const short* WT = (m == 0) ? WqT : (m == 1) ? WkT : WvT;
    float*       O  = (m == 0) ? Qo  : (m == 1) ? Ko  : Vo;
    f32x4 acc[8];
    #pragma unroll
    for (int nt = 0; nt < 8; ++nt) acc[nt] = (f32x4){0.f, 0.f, 0.f, 0.f};
    #pragma unroll
    for (int kc = 0; kc < 4; ++kc) {
      #pragma unroll
      for (int nt = 0; nt < 8; ++nt) {
        // B: col = lane&15, k = (lane>>4)*8 + j (+32*kc)
        short8 bfr = *(const short8*)(WT + (size_t)(nt * 16 + c) * 128 + kc * 32 + a * 8);
        acc[nt] = __builtin_amdgcn_mfma_f32_16x16x32_bf16(af[kc], bfr, acc[nt], 0, 0, 0);
      }
    }
    #pragma unroll
    for (int nt = 0; nt < 8; ++nt) {
      #pragma unroll
      for (int rr = 0; rr < 4; ++rr) {
        int row = rowbase + 4 * a + rr;  // D: col = lane&15, row = (lane>>4)*4 + reg
        if (row < nrows)
          O[(size_t)row * 128 + nt * 16 + c] = acc[nt][rr];
      }
    }
  }
}

// ---------- CSR build: zero counts ----------
__global__ __launch_bounds__(256) void zero_int_kernel(int* __restrict__ p, int n) {
  int t = blockIdx.x * 256 + threadIdx.x;
  if (t < n) p[t] = 0;
}

// ---------- CSR build: in-degree histogram ----------
__global__ __launch_bounds__(256) void count_kernel(const int* __restrict__ ei,
                                                    int* __restrict__ cnt, int nE) {
  int t = blockIdx.x * 256 + threadIdx.x;
  if (t < nE) atomicAdd(&cnt[ei[nE + t]], 1);
}

// ---------- CSR build: single-block exclusive scan (1024 thr, Hillis-Steele) ----------
__global__ __launch_bounds__(1024) void scan_kernel(int* __restrict__ cur,
                                                    int* __restrict__ rowptr, int n) {
  __shared__ int sdata[1024];
  const int tid = threadIdx.x;
  int run = 0;
  for (int chunk = 0; chunk < n; chunk += 1024) {
    int i = chunk + tid;
    int v = (i < n) ? cur[i] : 0;
    sdata[tid] = v;
    __syncthreads();
    #pragma unroll
    for (int off = 1; off < 1024; off <<= 1) {
      int t = (tid >= off) ? sdata[tid - off] : 0;
      __syncthreads();
      sdata[tid] += t;
      __syncthreads();
    }
    int incl = sdata[tid];
    int tot  = sdata[1023];
    __syncthreads();  // protect sdata[1023] against next chunk's writes
    if (i < n) {
      int excl = run + incl - v;
      rowptr[i] = excl;
      cur[i]    = excl;
    }
    run += tot;
  }
  if (tid == 0) rowptr[n] = run;
}

// ---------- CSR build: scatter src ids into dst-sorted order ----------
__global__ __launch_bounds__(256) void scatter_kernel(const int* __restrict__ ei,
                                                      int* __restrict__ cur,
                                                      int* __restrict__ esorted, int nE) {
  int t = blockIdx.x * 256 + threadIdx.x;
  if (t < nE) {
    int d = ei[nE + t];
    int p = atomicAdd(&cur[d], 1);
    esorted[p] = ei[t];
  }
}

// ---------- K2-4 fused: per-node online-softmax attention over CSR ----------
__global__ __launch_bounds__(256) void attn_kernel(
    const int* __restrict__ rowptr, const int* __restrict__ esorted,
    const float* __restrict__ Q, const float* __restrict__ K,
    const float* __restrict__ V, float* __restrict__ att) {
  int wid  = (blockIdx.x * 256 + threadIdx.x) >> 6;
  int lane = threadIdx.x & 63;
  if (wid >= N_NODES) return;
  int beg = rowptr[wid], end = rowptr[wid + 1];
  float2 q = ((const float2*)(Q + (size_t)wid * DIM))[lane];
  q.x *= 0.25f; q.y *= 0.25f;  // 1/sqrt(16)
  float m = -__int_as_float(0x7f800000);  // -inf
  float den = 0.f;
  float2 acc = make_float2(0.f, 0.f);
  int i = beg;
  for (; i + 1 < end; i += 2) {
    int s0 = esorted[i], s1 = esorted[i + 1];
    float2 k0 = ((const float2*)(K + (size_t)s0 * DIM))[lane];
    float2 v0 = ((const float2*)(V + (size_t)s0 * DIM))[lane];
    float2 k1 = ((const float2*)(K + (size_t)s1 * DIM))[lane];
    float2 v1 = ((const float2*)(V + (size_t)s1 * DIM))[lane];
    float sa = q.x * k0.x + q.y * k0.y;
    sa += __shfl_xor(sa, 1); sa += __shfl_xor(sa, 2); sa += __shfl_xor(sa, 4);
    float sb = q.x * k1.x + q.y * k1.y;
    sb += __shfl_xor(sb, 1); sb += __shfl_xor(sb, 2); sb += __shfl_xor(sb, 4);
    {
      float mn = fmaxf(m, sa);
      float sc = expf(m - mn), w = expf(sa - mn);
      den = den * sc + w;
      acc.x = acc.x * sc + w * v0.x;
      acc.y = acc.y * sc + w * v0.y;
      m = mn;
    }
    {
      float mn = fmaxf(m, sb);
      float sc = expf(m - mn), w = expf(sb - mn);
      den = den * sc + w;
      acc.x = acc.x * sc + w * v1.x;
      acc.y = acc.y * sc + w * v1.y;
      m = mn;
    }
  }
  if (i < end) {
    int s0 = esorted[i];
    float2 k0 = ((const float2*)(K + (size_t)s0 * DIM))[lane];
    float2 v0 = ((const float2*)(V + (size_t)s0 * DIM))[lane];
    float sa = q.x * k0.x + q.y * k0.y;
    sa += __shfl_xor(sa, 1); sa += __shfl_xor(sa, 2); sa += __shfl_xor(sa, 4);
    float mn = fmaxf(m, sa);
    float sc = expf(m - mn), w = expf(sa - mn);
    den = den * sc + w;
    acc.x = acc.x * sc + w * v0.x;
    acc.y = acc.y * sc + w * v0.y;
    m = mn;
  }
  float inv = 1.f / (den + 1e-16f);
  ((float2*)(att + (size_t)wid * DIM))[lane] = make_float2(acc.x * inv, acc.y * inv);
}

// ---------- K5/K6b: out = LN((a+b)/2)*g + be (+ optional bf16 copy) ----------
__global__ __launch_bounds__(256) void add_ln_kernel(
    const float* __restrict__ a, const float* __restrict__ b,
    const float* __restrict__ g, const float* __restrict__ be,
    float* __restrict__ out, short* __restrict__ ybf, int nrows) {
  int wave = (blockIdx.x * 256 + threadIdx.x) >> 6;
  int lane = threadIdx.x & 63;
  if (wave >= nrows) return;
  float2 av = ((const float2*)a)[(size_t)wave * 64 + lane];
  float2 bv = ((const float2*)b)[(size_t)wave * 64 + lane];
  float y0 = (av.x + bv.x) * 0.5f, y1 = (av.y + bv.y) * 0.5f;
  float s = y0 + y1;
  #pragma unroll
  for (int off = 32; off; off >>= 1) s += __shfl_xor(s, off);
  float mean = s * (1.0f / 128.0f);
  float d0 = y0 - mean, d1 = y1 - mean;
  float v = d0 * d0 + d1 * d1;
  #pragma unroll
  for (int off = 32; off; off >>= 1) v += __shfl_xor(v, off);
  float rstd = 1.0f / sqrtf(v * (1.0f / 128.0f) + 1e-5f);
  float2 gv = ((const float2*)g)[lane];
  float2 bev = ((const float2*)be)[lane];
  float2 o;
  o.x = gv.x * d0 * rstd + bev.x;
  o.y = gv.y * d1 * rstd + bev.y;
  ((float2*)out)[(size_t)wave * 64 + lane] = o;
  if (ybf) {
    unsigned pk = (unsigned short)f2bf(o.x) | ((unsigned)(unsigned short)f2bf(o.y) << 16);
    ((unsigned*)ybf)[(size_t)wave * 64 + lane] = pk;
  }
}

// ---------- K6: bf16-MFMA fused FFN (unchanged, HW-validated R3) ----------
__global__ __launch_bounds__(256) void ffn_mfma_kernel(
    const short* __restrict__ Ybf, const short* __restrict__ W1T,
    const float* __restrict__ b1, const short* __restrict__ W2T,
    const float* __restrict__ b2, float* __restrict__ ff, int nrows) {
  __shared__ float Hlds[4 * 16 * 40];  // 10240 B, per-wave 16x40 region
  const int tid = threadIdx.x;
  const int w = tid >> 6, lane = tid & 63;
  const int a = lane >> 4, c = lane & 15;
  const int rowbase = blockIdx.x * 64 + w * 16;
  float* Hw = Hlds + w * (16 * 40);

  short8 af[4];
  {
    int r = rowbase + c;
    if (r < nrows) {
      const short* yp = Ybf + (size_t)r * 128 + a * 8;
      #pragma unroll
      for (int kc = 0; kc < 4; ++kc)
        af[kc] = *(const short8*)(yp + kc * 32);
    } else {
      short8 z = {0, 0, 0, 0, 0, 0, 0, 0};
      #pragma unroll
      for (int kc = 0; kc < 4; ++kc) af[kc] = z;
    }
  }

  f32x4 acc2[8];
  #pragma unroll
  for (int i = 0; i < 8; ++i) acc2[i] = (f32x4){0.f, 0.f, 0.f, 0.f};

  for (int hc = 0; hc < 16; ++hc) {
    f32x4 acc1[2];
    acc1[0] = (f32x4){0.f, 0.f, 0.f, 0.f};
    acc1[1] = (f32x4){0.f, 0.f, 0.f, 0.f};
    #pragma unroll
    for (int t = 0; t < 2; ++t) {
      const short* wp = W1T + (size_t)(hc * 32 + t * 16 + c) * 128 + a * 8;
      #pragma unroll
      for (int kc = 0; kc < 4; ++kc) {
        short8 bfr = *(const short8*)(wp + kc * 32);
        acc1[t] = __builtin_amdgcn_mfma_f32_16x16x32_bf16(af[kc], bfr, acc1[t], 0, 0, 0);
      }
    }
    #pragma unroll
    for (int t = 0; t < 2; ++t) {
      float b1v = b1[hc * 32 + t * 16 + c];
      #pragma unroll
      for (int r = 0; r < 4; ++r) {
        float hv = fmaxf(acc1[t][r] + b1v, 0.f);
        Hw[(4 * a + r) * 40 + t * 16 + c] = hv;
      }
    }
    __syncthreads();
    float4 h0 = *(const float4*)(Hw + c * 40 + a * 8);
    float4 h1 = *(const float4*)(Hw + c * 40 + a * 8 + 4);
    short8 a2;
    a2[0] = f2bf(h0.x); a2[1] = f2bf(h0.y); a2[2] = f2bf(h0.z); a2[3] = f2bf(h0.w);
    a2[4] = f2bf(h1.x); a2[5] = f2bf(h1.y); a2[6] = f2bf(h1.z); a2[7] = f2bf(h1.w);
    __syncthreads();
    #pragma unroll
    for (int nt = 0; nt < 8; ++nt) {
      const short* wp = W2T + (size_t)(nt * 16 + c) * 512 + hc * 32 + a * 8;
      short8 bfr = *(const short8*)wp;
      acc2[nt] = __builtin_amdgcn_mfma_f32_16x16x32_bf16(a2, bfr, acc2[nt], 0, 0, 0);
    }
  }
  #pragma unroll
  for (int nt = 0; nt < 8; ++nt) {
    float b2v = b2[nt * 16 + c];
    #pragma unroll
    for (int r = 0; r < 4; ++r) {
      int row = rowbase + 4 * a + r;
      if (row < nrows)
        ff[(size_t)row * 128 + nt * 16 + c] = acc2[nt][r] + b2v;
    }
  }
}

// ---------- K8: in-place scale of output ----------
__global__ __launch_bounds__(256) void scale_kernel(float4* __restrict__ out,
                                                    const float* __restrict__ scl,
                                                    int n4) {
  int t = blockIdx.x * 256 + threadIdx.x;
  if (t < n4) {
    float s = scl[0];
    float4 v = out[t];
    v.x *= s; v.y *= s; v.z *= s; v.w *= s;
    out[t] = v;
  }
}

extern "C" void kernel_launch(void* const* d_in, const int* in_sizes, int n_in,
                              void* d_out, int out_size, void* d_ws, size_t ws_size,
                              hipStream_t stream) {
  const float* x   = (const float*)d_in[0];
  const int*   ei  = (const int*)  d_in[1];
  const float* Wq  = (const float*)d_in[2];
  const float* Wk  = (const float*)d_in[3];
  const float* Wv  = (const float*)d_in[4];
  const float* W1  = (const float*)d_in[5];
  const float* b1  = (const float*)d_in[6];
  const float* W2  = (const float*)d_in[7];
  const float* b2  = (const float*)d_in[8];
  const float* g1  = (const float*)d_in[9];
  const float* be1 = (const float*)d_in[10];
  const float* g2  = (const float*)d_in[11];
  const float* be2 = (const float*)d_in[12];
  float* out = (float*)d_out;
  float* ws  = (float*)d_ws;

  const size_t ND = (size_t)N_NODES * DIM;  // 6,400,000 floats

  // ---- workspace layout (u32 units from ws base), total ~105.6 MB ----
  float* CR0    = ws;      // ws[0]
  float* SCL    = ws + 1;  // ws[1]
  int*   ROWPTR = (int*)(ws + 16);            // 50001 (+pad to 50016)
  int*   CUR    = (int*)(ws + 16 + 50016);    // 50000 (counts, then cursors)
  int*   ESORT  = CUR + 50000;                // 600000
  short* W1T    = (short*)(ws + 700032);      // 65536 shorts
  short* W2T    = W1T + 65536;                // 65536 shorts
  short* WqT    = W2T + 65536;                // 16384 shorts
  short* WkT    = WqT + 16384;                // 16384 shorts
  short* WvT    = WkT + 16384;                // 16384 shorts
  float* Q      = ws + 790144;                // 16B-aligned
  float* K      = Q + ND;
  float* V      = K + ND;
  float* ATT    = V + ND;
  short* YBF    = (short*)Q;  // alias: Q dead after attn_kernel
  float* Y      = K;          // alias: K dead after attn_kernel
  float* FF     = V;          // alias: V dead after attn_kernel

  // 0. weight transposes -> bf16 (tiny)
  convw_kernel<<<512, 256, 0, stream>>>(W1, W2, W1T, W2T);
  convqkv_kernel<<<192, 256, 0, stream>>>(Wq, Wk, Wv, WqT, WkT, WvT);
  // 1. cr0 from raw x rows 0..3
  cr_kernel<<<1, 128, 0, stream>>>(x, 0.0f, 0, nullptr, CR0);
  // 2. Q,K,V GEMMs — bf16 MFMA
  qkv_mfma_kernel<<<(N_NODES + 63) / 64, 256, 0, stream>>>(x, WqT, WkT, WvT, Q, K, V, N_NODES);
  // 3. CSR build: histogram -> scan -> scatter
  zero_int_kernel<<<(N_NODES + 255) / 256, 256, 0, stream>>>(CUR, N_NODES);
  count_kernel<<<(N_EDGES + 255) / 256, 256, 0, stream>>>(ei, CUR, N_EDGES);
  scan_kernel<<<1, 1024, 0, stream>>>(CUR, ROWPTR, N_NODES);
  scatter_kernel<<<(N_EDGES + 255) / 256, 256, 0, stream>>>(ei, CUR, ESORT, N_EDGES);
  // 4. fused attention: one wave per node, online softmax, no atomics
  attn_kernel<<<N_NODES / 4, 256, 0, stream>>>(ROWPTR, ESORT, Q, K, V, ATT);
  // 5. y = LN1((x+att)/2)  (+ bf16 copy for FFN, into dead Q region)
  add_ln_kernel<<<N_NODES / 4, 256, 0, stream>>>(x, ATT, g1, be1, Y, YBF, N_NODES);
  // 6. ff = FFN(y)  — bf16 MFMA
  ffn_mfma_kernel<<<(N_NODES + 63) / 64, 256, 0, stream>>>(YBF, W1T, b1, W2T, b2, FF, N_NODES);
  // 7. z = LN2((y+ff)/2) -> d_out
  add_ln_kernel<<<N_NODES / 4, 256, 0, stream>>>(Y, FF, g2, be2, out, nullptr, N_NODES);
  // 8. cr on z, scale factor -> SCL
  cr_kernel<<<1, 128, 0, stream>>>(out, 1.0f, 1, CR0, SCL);
  // 9. out *= scale
  scale_kernel<<<(int)(ND / 4 / 256), 256, 0, stream>>>((float4*)out, SCL, (int)(ND / 4));
}

// Round 10
// 550.271 us; speedup vs baseline: 2.3811x; 1.0019x over previous
//
#include <hip/hip_runtime.h>
#include <hip/hip_bf16.h>
#include <math.h>

#define N_NODES 50000
#define N_EDGES 600000
#define DIM     128
#define NHEAD   8
#define DHEAD   16
#define DFF     512

typedef __attribute__((ext_vector_type(8))) short short8;
typedef __attribute__((ext_vector_type(4))) float f32x4;

__device__ __forceinline__ short f2bf(float f) {
  __hip_bfloat16 h = __float2bfloat16(f);
  union { __hip_bfloat16 h; short s; } u; u.h = h; return u.s;
}

// ---------- K0/K7: cross-ratio from 4 rows of a [*,128] matrix ----------
__global__ __launch_bounds__(128) void cr_kernel(const float* __restrict__ x,
                                                 float addone, int mode,
                                                 const float* __restrict__ cr0p,
                                                 float* __restrict__ out) {
  __shared__ float red[4][2];
  const int t = threadIdx.x, lane = t & 63, w = t >> 6;
  float a = x[t], b = x[128 + t], c = x[256 + t], d = x[384 + t];
  float pac = a * c, pbd = b * d, pad = a * d, pbc = b * c;
  #pragma unroll
  for (int off = 32; off; off >>= 1) {
    pac += __shfl_xor(pac, off);
    pbd += __shfl_xor(pbd, off);
    pad += __shfl_xor(pad, off);
    pbc += __shfl_xor(pbc, off);
  }
  if (lane == 0) { red[0][w] = pac; red[1][w] = pbd; red[2][w] = pad; red[3][w] = pbc; }
  __syncthreads();
  if (t == 0) {
    float ac = red[0][0] + red[0][1] + addone;
    float bd = red[1][0] + red[1][1] + addone;
    float ad = red[2][0] + red[2][1] + addone;
    float bc = red[3][0] + red[3][1] + addone;
    float cr = ac * bd / (ad * bc + 1e-8f);
    if (mode == 0) {
      out[0] = cr;
    } else {
      float cr0 = cr0p[0];
      bool fin_cr  = (cr == cr)  && (fabsf(cr)  < __int_as_float(0x7f800000));
      bool fin_cr0 = (cr0 == cr0) && (fabsf(cr0) < __int_as_float(0x7f800000));
      bool valid = fin_cr && fin_cr0 && (fabsf(cr) > 1e-8f);
      float scale = 1.0f;
      if (valid) scale = sqrtf(sqrtf(fabsf(cr0 / cr)));
      out[0] = scale;
    }
  }
}

// ---------- weight transpose + bf16 convert: W1T[512][128], W2T[128][512] ----------
__global__ __launch_bounds__(256) void convw_kernel(
    const float* __restrict__ W1, const float* __restrict__ W2,
    short* __restrict__ W1T, short* __restrict__ W2T) {
  int t = blockIdx.x * 256 + threadIdx.x;
  if (t < 512 * 128) {
    int n = t >> 7, k = t & 127;               // W1T[n][k] = W1[k][n]
    W1T[t] = f2bf(W1[(size_t)k * 512 + n]);
  } else {
    int i = t - 512 * 128;
    int n = i >> 9, k = i & 511;               // W2T[n][k] = W2[k][n]
    W2T[i] = f2bf(W2[(size_t)k * 128 + n]);
  }
}

// ---------- Wq/Wk/Wv transpose + bf16 convert: each [128][128] ----------
__global__ __launch_bounds__(256) void convqkv_kernel(
    const float* __restrict__ Wq, const float* __restrict__ Wk,
    const float* __restrict__ Wv, short* __restrict__ WqT,
    short* __restrict__ WkT, short* __restrict__ WvT) {
  int t = blockIdx.x * 256 + threadIdx.x;  // 0..49151
  int m = t >> 14, i = t & 16383;
  int n = i >> 7, k = i & 127;             // WT[n][k] = W[k][n]
  const float* W = (m == 0) ? Wq : (m == 1) ? Wk : Wv;
  short*      WT = (m == 0) ? WqT : (m == 1) ? WkT : WvT;
  WT[i] = f2bf(W[(size_t)k * 128 + n]);
}

// ---------- K1: bf16-MFMA QKV GEMM (HW-validated R9: absmax unchanged) ----------
__global__ __launch_bounds__(256) void qkv_mfma_kernel(
    const float* __restrict__ x, const short* __restrict__ WqT,
    const short* __restrict__ WkT, const short* __restrict__ WvT,
    float* __restrict__ Qo, float* __restrict__ Ko, float* __restrict__ Vo,
    int nrows) {
  const int tid = threadIdx.x;
  const int w = tid >> 6, lane = tid & 63;
  const int a = lane >> 4, c = lane & 15;
  const int rowbase = blockIdx.x * 64 + w * 16;

  short8 af[4];
  {
    int r = rowbase + c;  // A: row = lane&15, k = (lane>>4)*8 + j (+32*kc)
    if (r < nrows) {
      const float* xp = x + (size_t)r * 128 + a * 8;
      #pragma unroll
      for (int kc = 0; kc < 4; ++kc) {
        float4 x0 = *(const float4*)(xp + kc * 32);
        float4 x1 = *(const float4*)(xp + kc * 32 + 4);
        short8 v;
        v[0] = f2bf(x0.x); v[1] = f2bf(x0.y); v[2] = f2bf(x0.z); v[3] = f2bf(x0.w);
        v[4] = f2bf(x1.x); v[5] = f2bf(x1.y); v[6] = f2bf(x1.z); v[7] = f2bf(x1.w);
        af[kc] = v;
      }
    } else {
      short8 z = {0, 0, 0, 0, 0, 0, 0, 0};
      #pragma unroll
      for (int kc = 0; kc < 4; ++kc) af[kc] = z;
    }
  }

  #pragma unroll
  for (int m = 0; m < 3; ++m) {
    const short* WT = (m == 0) ? WqT : (m == 1) ? WkT : WvT;
    float*       O  = (m == 0) ? Qo  : (m == 1) ? Ko  : Vo;
    f32x4 acc[8];
    #pragma unroll
    for (int nt = 0; nt < 8; ++nt) acc[nt] = (f32x4){0.f, 0.f, 0.f, 0.f};
    #pragma unroll
    for (int kc = 0; kc < 4; ++kc) {
      #pragma unroll
      for (int nt = 0; nt < 8; ++nt) {
        short8 bfr = *(const short8*)(WT + (size_t)(nt * 16 + c) * 128 + kc * 32 + a * 8);
        acc[nt] = __builtin_amdgcn_mfma_f32_16x16x32_bf16(af[kc], bfr, acc[nt], 0, 0, 0);
      }
    }
    #pragma unroll
    for (int nt = 0; nt < 8; ++nt) {
      #pragma unroll
      for (int rr = 0; rr < 4; ++rr) {
        int row = rowbase + 4 * a + rr;  // D: col = lane&15, row = (lane>>4)*4 + reg
        if (row < nrows)
          O[(size_t)row * 128 + nt * 16 + c] = acc[nt][rr];
      }
    }
  }
}

// ---------- CSR build: zero counts ----------
__global__ __launch_bounds__(256) void zero_int_kernel(int* __restrict__ p, int n) {
  int t = blockIdx.x * 256 + threadIdx.x;
  if (t < n) p[t] = 0;
}

// ---------- CSR build: in-degree histogram ----------
__global__ __launch_bounds__(256) void count_kernel(const int* __restrict__ ei,
                                                    int* __restrict__ cnt, int nE) {
  int t = blockIdx.x * 256 + threadIdx.x;
  if (t < nE) atomicAdd(&cnt[ei[nE + t]], 1);
}

// ---------- CSR build: single-block exclusive scan (1024 thr, Hillis-Steele) ----------
__global__ __launch_bounds__(1024) void scan_kernel(int* __restrict__ cur,
                                                    int* __restrict__ rowptr, int n) {
  __shared__ int sdata[1024];
  const int tid = threadIdx.x;
  int run = 0;
  for (int chunk = 0; chunk < n; chunk += 1024) {
    int i = chunk + tid;
    int v = (i < n) ? cur[i] : 0;
    sdata[tid] = v;
    __syncthreads();
    #pragma unroll
    for (int off = 1; off < 1024; off <<= 1) {
      int t = (tid >= off) ? sdata[tid - off] : 0;
      __syncthreads();
      sdata[tid] += t;
      __syncthreads();
    }
    int incl = sdata[tid];
    int tot  = sdata[1023];
    __syncthreads();  // protect sdata[1023] against next chunk's writes
    if (i < n) {
      int excl = run + incl - v;
      rowptr[i] = excl;
      cur[i]    = excl;
    }
    run += tot;
  }
  if (tid == 0) rowptr[n] = run;
}

// ---------- CSR build: scatter src ids into dst-sorted order ----------
__global__ __launch_bounds__(256) void scatter_kernel(const int* __restrict__ ei,
                                                      int* __restrict__ cur,
                                                      int* __restrict__ esorted, int nE) {
  int t = blockIdx.x * 256 + threadIdx.x;
  if (t < nE) {
    int d = ei[nE + t];
    int p = atomicAdd(&cur[d], 1);
    esorted[p] = ei[t];
  }
}

// ---------- K2-4 fused: per-node online-softmax attention over CSR ----------
__global__ __launch_bounds__(256) void attn_kernel(
    const int* __restrict__ rowptr, const int* __restrict__ esorted,
    const float* __restrict__ Q, const float* __restrict__ K,
    const float* __restrict__ V, float* __restrict__ att) {
  int wid  = (blockIdx.x * 256 + threadIdx.x) >> 6;
  int lane = threadIdx.x & 63;
  if (wid >= N_NODES) return;
  int beg = rowptr[wid], end = rowptr[wid + 1];
  float2 q = ((const float2*)(Q + (size_t)wid * DIM))[lane];
  q.x *= 0.25f; q.y *= 0.25f;  // 1/sqrt(16)
  float m = -__int_as_float(0x7f800000);  // -inf
  float den = 0.f;
  float2 acc = make_float2(0.f, 0.f);
  int i = beg;
  for (; i + 1 < end; i += 2) {
    int s0 = esorted[i], s1 = esorted[i + 1];
    float2 k0 = ((const float2*)(K + (size_t)s0 * DIM))[lane];
    float2 v0 = ((const float2*)(V + (size_t)s0 * DIM))[lane];
    float2 k1 = ((const float2*)(K + (size_t)s1 * DIM))[lane];
    float2 v1 = ((const float2*)(V + (size_t)s1 * DIM))[lane];
    float sa = q.x * k0.x + q.y * k0.y;
    sa += __shfl_xor(sa, 1); sa += __shfl_xor(sa, 2); sa += __shfl_xor(sa, 4);
    float sb = q.x * k1.x + q.y * k1.y;
    sb += __shfl_xor(sb, 1); sb += __shfl_xor(sb, 2); sb += __shfl_xor(sb, 4);
    {
      float mn = fmaxf(m, sa);
      float sc = expf(m - mn), w = expf(sa - mn);
      den = den * sc + w;
      acc.x = acc.x * sc + w * v0.x;
      acc.y = acc.y * sc + w * v0.y;
      m = mn;
    }
    {
      float mn = fmaxf(m, sb);
      float sc = expf(m - mn), w = expf(sb - mn);
      den = den * sc + w;
      acc.x = acc.x * sc + w * v1.x;
      acc.y = acc.y * sc + w * v1.y;
      m = mn;
    }
  }
  if (i < end) {
    int s0 = esorted[i];
    float2 k0 = ((const float2*)(K + (size_t)s0 * DIM))[lane];
    float2 v0 = ((const float2*)(V + (size_t)s0 * DIM))[lane];
    float sa = q.x * k0.x + q.y * k0.y;
    sa += __shfl_xor(sa, 1); sa += __shfl_xor(sa, 2); sa += __shfl_xor(sa, 4);
    float mn = fmaxf(m, sa);
    float sc = expf(m - mn), w = expf(sa - mn);
    den = den * sc + w;
    acc.x = acc.x * sc + w * v0.x;
    acc.y = acc.y * sc + w * v0.y;
    m = mn;
  }
  float inv = 1.f / (den + 1e-16f);
  ((float2*)(att + (size_t)wid * DIM))[lane] = make_float2(acc.x * inv, acc.y * inv);
}

// ---------- K5/K6b: out = LN((a+b)/2)*g + be (+ optional bf16 copy) ----------
__global__ __launch_bounds__(256) void add_ln_kernel(
    const float* __restrict__ a, const float* __restrict__ b,
    const float* __restrict__ g, const float* __restrict__ be,
    float* __restrict__ out, short* __restrict__ ybf, int nrows) {
  int wave = (blockIdx.x * 256 + threadIdx.x) >> 6;
  int lane = threadIdx.x & 63;
  if (wave >= nrows) return;
  float2 av = ((const float2*)a)[(size_t)wave * 64 + lane];
  float2 bv = ((const float2*)b)[(size_t)wave * 64 + lane];
  float y0 = (av.x + bv.x) * 0.5f, y1 = (av.y + bv.y) * 0.5f;
  float s = y0 + y1;
  #pragma unroll
  for (int off = 32; off; off >>= 1) s += __shfl_xor(s, off);
  float mean = s * (1.0f / 128.0f);
  float d0 = y0 - mean, d1 = y1 - mean;
  float v = d0 * d0 + d1 * d1;
  #pragma unroll
  for (int off = 32; off; off >>= 1) v += __shfl_xor(v, off);
  float rstd = 1.0f / sqrtf(v * (1.0f / 128.0f) + 1e-5f);
  float2 gv = ((const float2*)g)[lane];
  float2 bev = ((const float2*)be)[lane];
  float2 o;
  o.x = gv.x * d0 * rstd + bev.x;
  o.y = gv.y * d1 * rstd + bev.y;
  ((float2*)out)[(size_t)wave * 64 + lane] = o;
  if (ybf) {
    unsigned pk = (unsigned short)f2bf(o.x) | ((unsigned)(unsigned short)f2bf(o.y) << 16);
    ((unsigned*)ybf)[(size_t)wave * 64 + lane] = pk;
  }
}

// ---------- K6: bf16-MFMA fused FFN ----------
// R10 changes vs R9 (counter-driven):
//  * LDS H stride 40 -> 36 floats: write a-stride 144%32=16 -> 2-way (free,
//    m136); float4 read start banks (4c+8a)%32 -> each 8-lane group covers
//    all 32 banks -> conflict-free. (stride 40 was 4-way on writes:
//    SQ_LDS_BANK_CONFLICT = 4.7M cycles/dispatch.)
//  * __syncthreads -> s_waitcnt lgkmcnt(0) + compiler fence: LDS region is
//    PER-WAVE (cross-lane RAW only); LDS ops execute in issue order within a
//    wave, so a full block barrier over-synchronizes the 4 waves and was the
//    main serialization (MfmaUtil 4%, VALUBusy 7%, Occ 27% -- nothing busy).
__global__ __launch_bounds__(256) void ffn_mfma_kernel(
    const short* __restrict__ Ybf, const short* __restrict__ W1T,
    const float* __restrict__ b1, const short* __restrict__ W2T,
    const float* __restrict__ b2, float* __restrict__ ff, int nrows) {
  __shared__ float Hlds[4 * 16 * 36];  // 9216 B, per-wave 16x36 region
  const int tid = threadIdx.x;
  const int w = tid >> 6, lane = tid & 63;
  const int a = lane >> 4, c = lane & 15;
  const int rowbase = blockIdx.x * 64 + w * 16;
  float* Hw = Hlds + w * (16 * 36);

  short8 af[4];
  {
    int r = rowbase + c;
    if (r < nrows) {
      const short* yp = Ybf + (size_t)r * 128 + a * 8;
      #pragma unroll
      for (int kc = 0; kc < 4; ++kc)
        af[kc] = *(const short8*)(yp + kc * 32);
    } else {
      short8 z = {0, 0, 0, 0, 0, 0, 0, 0};
      #pragma unroll
      for (int kc = 0; kc < 4; ++kc) af[kc] = z;
    }
  }

  f32x4 acc2[8];
  #pragma unroll
  for (int i = 0; i < 8; ++i) acc2[i] = (f32x4){0.f, 0.f, 0.f, 0.f};

  for (int hc = 0; hc < 16; ++hc) {
    f32x4 acc1[2];
    acc1[0] = (f32x4){0.f, 0.f, 0.f, 0.f};
    acc1[1] = (f32x4){0.f, 0.f, 0.f, 0.f};
    #pragma unroll
    for (int t = 0; t < 2; ++t) {
      const short* wp = W1T + (size_t)(hc * 32 + t * 16 + c) * 128 + a * 8;
      #pragma unroll
      for (int kc = 0; kc < 4; ++kc) {
        short8 bfr = *(const short8*)(wp + kc * 32);
        acc1[t] = __builtin_amdgcn_mfma_f32_16x16x32_bf16(af[kc], bfr, acc1[t], 0, 0, 0);
      }
    }
    // bias + relu, stash H chunk (rows = 4a+r, cols = t*16+c) in wave LDS
    #pragma unroll
    for (int t = 0; t < 2; ++t) {
      float b1v = b1[hc * 32 + t * 16 + c];
      #pragma unroll
      for (int r = 0; r < 4; ++r) {
        float hv = fmaxf(acc1[t][r] + b1v, 0.f);
        Hw[(4 * a + r) * 36 + t * 16 + c] = hv;
      }
    }
    // wave-internal RAW: LDS ops are in-order per wave; wait for writes and
    // fence the compiler (no cross-wave dependency -> no s_barrier needed).
    asm volatile("s_waitcnt lgkmcnt(0)" ::: "memory");
    float4 h0 = *(const float4*)(Hw + c * 36 + a * 8);
    float4 h1 = *(const float4*)(Hw + c * 36 + a * 8 + 4);
    short8 a2;
    a2[0] = f2bf(h0.x); a2[1] = f2bf(h0.y); a2[2] = f2bf(h0.z); a2[3] = f2bf(h0.w);
    a2[4] = f2bf(h1.x); a2[5] = f2bf(h1.y); a2[6] = f2bf(h1.z); a2[7] = f2bf(h1.w);
    // WAR guard: keep next iteration's LDS writes from being hoisted above
    // the reads (in-order LDS makes the wait itself sufficient).
    asm volatile("s_waitcnt lgkmcnt(0)" ::: "memory");
    #pragma unroll
    for (int nt = 0; nt < 8; ++nt) {
      const short* wp = W2T + (size_t)(nt * 16 + c) * 512 + hc * 32 + a * 8;
      short8 bfr = *(const short8*)wp;
      acc2[nt] = __builtin_amdgcn_mfma_f32_16x16x32_bf16(a2, bfr, acc2[nt], 0, 0, 0);
    }
  }
  #pragma unroll
  for (int nt = 0; nt < 8; ++nt) {
    float b2v = b2[nt * 16 + c];
    #pragma unroll
    for (int r = 0; r < 4; ++r) {
      int row = rowbase + 4 * a + r;
      if (row < nrows)
        ff[(size_t)row * 128 + nt * 16 + c] = acc2[nt][r] + b2v;
    }
  }
}

// ---------- K8: in-place scale of output ----------
__global__ __launch_bounds__(256) void scale_kernel(float4* __restrict__ out,
                                                    const float* __restrict__ scl,
                                                    int n4) {
  int t = blockIdx.x * 256 + threadIdx.x;
  if (t < n4) {
    float s = scl[0];
    float4 v = out[t];
    v.x *= s; v.y *= s; v.z *= s; v.w *= s;
    out[t] = v;
  }
}

extern "C" void kernel_launch(void* const* d_in, const int* in_sizes, int n_in,
                              void* d_out, int out_size, void* d_ws, size_t ws_size,
                              hipStream_t stream) {
  const float* x   = (const float*)d_in[0];
  const int*   ei  = (const int*)  d_in[1];
  const float* Wq  = (const float*)d_in[2];
  const float* Wk  = (const float*)d_in[3];
  const float* Wv  = (const float*)d_in[4];
  const float* W1  = (const float*)d_in[5];
  const float* b1  = (const float*)d_in[6];
  const float* W2  = (const float*)d_in[7];
  const float* b2  = (const float*)d_in[8];
  const float* g1  = (const float*)d_in[9];
  const float* be1 = (const float*)d_in[10];
  const float* g2  = (const float*)d_in[11];
  const float* be2 = (const float*)d_in[12];
  float* out = (float*)d_out;
  float* ws  = (float*)d_ws;

  const size_t ND = (size_t)N_NODES * DIM;  // 6,400,000 floats

  // ---- workspace layout (u32 units from ws base), total ~105.6 MB ----
  float* CR0    = ws;      // ws[0]
  float* SCL    = ws + 1;  // ws[1]
  int*   ROWPTR = (int*)(ws + 16);            // 50001 (+pad to 50016)
  int*   CUR    = (int*)(ws + 16 + 50016);    // 50000 (counts, then cursors)
  int*   ESORT  = CUR + 50000;                // 600000
  short* W1T    = (short*)(ws + 700032);      // 65536 shorts
  short* W2T    = W1T + 65536;                // 65536 shorts
  short* WqT    = W2T + 65536;                // 16384 shorts
  short* WkT    = WqT + 16384;                // 16384 shorts
  short* WvT    = WkT + 16384;                // 16384 shorts
  float* Q      = ws + 790144;                // 16B-aligned
  float* K      = Q + ND;
  float* V      = K + ND;
  float* ATT    = V + ND;
  short* YBF    = (short*)Q;  // alias: Q dead after attn_kernel
  float* Y      = K;          // alias: K dead after attn_kernel
  float* FF     = V;          // alias: V dead after attn_kernel

  // 0. weight transposes -> bf16 (tiny)
  convw_kernel<<<512, 256, 0, stream>>>(W1, W2, W1T, W2T);
  convqkv_kernel<<<192, 256, 0, stream>>>(Wq, Wk, Wv, WqT, WkT, WvT);
  // 1. cr0 from raw x rows 0..3
  cr_kernel<<<1, 128, 0, stream>>>(x, 0.0f, 0, nullptr, CR0);
  // 2. Q,K,V GEMMs — bf16 MFMA
  qkv_mfma_kernel<<<(N_NODES + 63) / 64, 256, 0, stream>>>(x, WqT, WkT, WvT, Q, K, V, N_NODES);
  // 3. CSR build: histogram -> scan -> scatter
  zero_int_kernel<<<(N_NODES + 255) / 256, 256, 0, stream>>>(CUR, N_NODES);
  count_kernel<<<(N_EDGES + 255) / 256, 256, 0, stream>>>(ei, CUR, N_EDGES);
  scan_kernel<<<1, 1024, 0, stream>>>(CUR, ROWPTR, N_NODES);
  scatter_kernel<<<(N_EDGES + 255) / 256, 256, 0, stream>>>(ei, CUR, ESORT, N_EDGES);
  // 4. fused attention: one wave per node, online softmax, no atomics
  attn_kernel<<<N_NODES / 4, 256, 0, stream>>>(ROWPTR, ESORT, Q, K, V, ATT);
  // 5. y = LN1((x+att)/2)  (+ bf16 copy for FFN, into dead Q region)
  add_ln_kernel<<<N_NODES / 4, 256, 0, stream>>>(x, ATT, g1, be1, Y, YBF, N_NODES);
  // 6. ff = FFN(y)  — bf16 MFMA
  ffn_mfma_kernel<<<(N_NODES + 63) / 64, 256, 0, stream>>>(YBF, W1T, b1, W2T, b2, FF, N_NODES);
  // 7. z = LN2((y+ff)/2) -> d_out
  add_ln_kernel<<<N_NODES / 4, 256, 0, stream>>>(Y, FF, g2, be2, out, nullptr, N_NODES);
  // 8. cr on z, scale factor -> SCL
  cr_kernel<<<1, 128, 0, stream>>>(out, 1.0f, 1, CR0, SCL);
  // 9. out *= scale
  scale_kernel<<<(int)(ND / 4 / 256), 256, 0, stream>>>((float4*)out, SCL, (int)(ND / 4));
}

// Round 11
// 469.675 us; speedup vs baseline: 2.7897x; 1.1716x over previous
//
#include <hip/hip_runtime.h>
#include <hip/hip_bf16.h>
#include <math.h>

#define N_NODES 50000
#define N_EDGES 600000
#define DIM     128
#define NHEAD   8
#define DHEAD   16
#define DFF     512

typedef __attribute__((ext_vector_type(8))) short short8;
typedef __attribute__((ext_vector_type(4))) float f32x4;

__device__ __forceinline__ short f2bf(float f) {
  __hip_bfloat16 h = __float2bfloat16(f);
  union { __hip_bfloat16 h; short s; } u; u.h = h; return u.s;
}

// ---------- K0/K7: cross-ratio from 4 rows of a [*,128] matrix ----------
__global__ __launch_bounds__(128) void cr_kernel(const float* __restrict__ x,
                                                 float addone, int mode,
                                                 const float* __restrict__ cr0p,
                                                 float* __restrict__ out) {
  __shared__ float red[4][2];
  const int t = threadIdx.x, lane = t & 63, w = t >> 6;
  float a = x[t], b = x[128 + t], c = x[256 + t], d = x[384 + t];
  float pac = a * c, pbd = b * d, pad = a * d, pbc = b * c;
  #pragma unroll
  for (int off = 32; off; off >>= 1) {
    pac += __shfl_xor(pac, off);
    pbd += __shfl_xor(pbd, off);
    pad += __shfl_xor(pad, off);
    pbc += __shfl_xor(pbc, off);
  }
  if (lane == 0) { red[0][w] = pac; red[1][w] = pbd; red[2][w] = pad; red[3][w] = pbc; }
  __syncthreads();
  if (t == 0) {
    float ac = red[0][0] + red[0][1] + addone;
    float bd = red[1][0] + red[1][1] + addone;
    float ad = red[2][0] + red[2][1] + addone;
    float bc = red[3][0] + red[3][1] + addone;
    float cr = ac * bd / (ad * bc + 1e-8f);
    if (mode == 0) {
      out[0] = cr;
    } else {
      float cr0 = cr0p[0];
      bool fin_cr  = (cr == cr)  && (fabsf(cr)  < __int_as_float(0x7f800000));
      bool fin_cr0 = (cr0 == cr0) && (fabsf(cr0) < __int_as_float(0x7f800000));
      bool valid = fin_cr && fin_cr0 && (fabsf(cr) > 1e-8f);
      float scale = 1.0f;
      if (valid) scale = sqrtf(sqrtf(fabsf(cr0 / cr)));
      out[0] = scale;
    }
  }
}

// ---------- weight convert, FRAGMENT-MAJOR layout for the staged FFN ----------
// W1F: [hc:16][frag:8 = t*4+kc][lane:64][j:8] bf16  (8KB per hc-chunk)
//   value = W1[k][n], k = kc*32 + (l>>4)*8 + j, n = hc*32 + t*16 + (l&15)
// W2F: [hc:16][frag:8 = nt][lane:64][j:8] bf16      (8KB per hc-chunk)
//   value = W2[k][n], k = hc*32 + (l>>4)*8 + j, n = nt*16 + (l&15)
// => per-iteration B chunk is CONTIGUOUS in global, LDS writes and all
//    B-fragment ds_read_b128 are linear in lane (conflict-free, no swizzle).
__global__ __launch_bounds__(256) void convw_kernel(
    const float* __restrict__ W1, const float* __restrict__ W2,
    short* __restrict__ W1F, short* __restrict__ W2F) {
  int o = blockIdx.x * 256 + threadIdx.x;  // 0..131071
  int q = o & 65535;
  int hc = q >> 12, r = q & 4095, f = r >> 9, l = (r >> 3) & 63, j = q & 7;
  int a = l >> 4, c = l & 15;
  if (o < 65536) {
    int t = f >> 2, kc = f & 3;
    int k = kc * 32 + a * 8 + j, n = hc * 32 + t * 16 + c;
    W1F[q] = f2bf(W1[(size_t)k * 512 + n]);
  } else {
    int nt = f;
    int k = hc * 32 + a * 8 + j, n = nt * 16 + c;
    W2F[q] = f2bf(W2[(size_t)k * 128 + n]);
  }
}

// ---------- Wq/Wk/Wv transpose + bf16 convert: each [128][128] ----------
__global__ __launch_bounds__(256) void convqkv_kernel(
    const float* __restrict__ Wq, const float* __restrict__ Wk,
    const float* __restrict__ Wv, short* __restrict__ WqT,
    short* __restrict__ WkT, short* __restrict__ WvT) {
  int t = blockIdx.x * 256 + threadIdx.x;  // 0..49151
  int m = t >> 14, i = t & 16383;
  int n = i >> 7, k = i & 127;             // WT[n][k] = W[k][n]
  const float* W = (m == 0) ? Wq : (m == 1) ? Wk : Wv;
  short*      WT = (m == 0) ? WqT : (m == 1) ? WkT : WvT;
  WT[i] = f2bf(W[(size_t)k * 128 + n]);
}

// ---------- K1: bf16-MFMA QKV GEMM (unchanged this round; port next) ----------
__global__ __launch_bounds__(256) void qkv_mfma_kernel(
    const float* __restrict__ x, const short* __restrict__ WqT,
    const short* __restrict__ WkT, const short* __restrict__ WvT,
    float* __restrict__ Qo, float* __restrict__ Ko, float* __restrict__ Vo,
    int nrows) {
  const int tid = threadIdx.x;
  const int w = tid >> 6, lane = tid & 63;
  const int a = lane >> 4, c = lane & 15;
  const int rowbase = blockIdx.x * 64 + w * 16;

  short8 af[4];
  {
    int r = rowbase + c;
    if (r < nrows) {
      const float* xp = x + (size_t)r * 128 + a * 8;
      #pragma unroll
      for (int kc = 0; kc < 4; ++kc) {
        float4 x0 = *(const float4*)(xp + kc * 32);
        float4 x1 = *(const float4*)(xp + kc * 32 + 4);
        short8 v;
        v[0] = f2bf(x0.x); v[1] = f2bf(x0.y); v[2] = f2bf(x0.z); v[3] = f2bf(x0.w);
        v[4] = f2bf(x1.x); v[5] = f2bf(x1.y); v[6] = f2bf(x1.z); v[7] = f2bf(x1.w);
        af[kc] = v;
      }
    } else {
      short8 z = {0, 0, 0, 0, 0, 0, 0, 0};
      #pragma unroll
      for (int kc = 0; kc < 4; ++kc) af[kc] = z;
    }
  }

  #pragma unroll
  for (int m = 0; m < 3; ++m) {
    const short* WT = (m == 0) ? WqT : (m == 1) ? WkT : WvT;
    float*       O  = (m == 0) ? Qo  : (m == 1) ? Ko  : Vo;
    f32x4 acc[8];
    #pragma unroll
    for (int nt = 0; nt < 8; ++nt) acc[nt] = (f32x4){0.f, 0.f, 0.f, 0.f};
    #pragma unroll
    for (int kc = 0; kc < 4; ++kc) {
      #pragma unroll
      for (int nt = 0; nt < 8; ++nt) {
        short8 bfr = *(const short8*)(WT + (size_t)(nt * 16 + c) * 128 + kc * 32 + a * 8);
        acc[nt] = __builtin_amdgcn_mfma_f32_16x16x32_bf16(af[kc], bfr, acc[nt], 0, 0, 0);
      }
    }
    #pragma unroll
    for (int nt = 0; nt < 8; ++nt) {
      #pragma unroll
      for (int rr = 0; rr < 4; ++rr) {
        int row = rowbase + 4 * a + rr;
        if (row < nrows)
          O[(size_t)row * 128 + nt * 16 + c] = acc[nt][rr];
      }
    }
  }
}

// ---------- CSR build: zero counts ----------
__global__ __launch_bounds__(256) void zero_int_kernel(int* __restrict__ p, int n) {
  int t = blockIdx.x * 256 + threadIdx.x;
  if (t < n) p[t] = 0;
}

// ---------- CSR build: in-degree histogram ----------
__global__ __launch_bounds__(256) void count_kernel(const int* __restrict__ ei,
                                                    int* __restrict__ cnt, int nE) {
  int t = blockIdx.x * 256 + threadIdx.x;
  if (t < nE) atomicAdd(&cnt[ei[nE + t]], 1);
}

// ---------- CSR build: single-block exclusive scan (1024 thr, Hillis-Steele) ----------
__global__ __launch_bounds__(1024) void scan_kernel(int* __restrict__ cur,
                                                    int* __restrict__ rowptr, int n) {
  __shared__ int sdata[1024];
  const int tid = threadIdx.x;
  int run = 0;
  for (int chunk = 0; chunk < n; chunk += 1024) {
    int i = chunk + tid;
    int v = (i < n) ? cur[i] : 0;
    sdata[tid] = v;
    __syncthreads();
    #pragma unroll
    for (int off = 1; off < 1024; off <<= 1) {
      int t = (tid >= off) ? sdata[tid - off] : 0;
      __syncthreads();
      sdata[tid] += t;
      __syncthreads();
    }
    int incl = sdata[tid];
    int tot  = sdata[1023];
    __syncthreads();
    if (i < n) {
      int excl = run + incl - v;
      rowptr[i] = excl;
      cur[i]    = excl;
    }
    run += tot;
  }
  if (tid == 0) rowptr[n] = run;
}

// ---------- CSR build: scatter src ids into dst-sorted order ----------
__global__ __launch_bounds__(256) void scatter_kernel(const int* __restrict__ ei,
                                                      int* __restrict__ cur,
                                                      int* __restrict__ esorted, int nE) {
  int t = blockIdx.x * 256 + threadIdx.x;
  if (t < nE) {
    int d = ei[nE + t];
    int p = atomicAdd(&cur[d], 1);
    esorted[p] = ei[t];
  }
}

// ---------- K2-4 fused: per-node online-softmax attention over CSR ----------
__global__ __launch_bounds__(256) void attn_kernel(
    const int* __restrict__ rowptr, const int* __restrict__ esorted,
    const float* __restrict__ Q, const float* __restrict__ K,
    const float* __restrict__ V, float* __restrict__ att) {
  int wid  = (blockIdx.x * 256 + threadIdx.x) >> 6;
  int lane = threadIdx.x & 63;
  if (wid >= N_NODES) return;
  int beg = rowptr[wid], end = rowptr[wid + 1];
  float2 q = ((const float2*)(Q + (size_t)wid * DIM))[lane];
  q.x *= 0.25f; q.y *= 0.25f;  // 1/sqrt(16)
  float m = -__int_as_float(0x7f800000);  // -inf
  float den = 0.f;
  float2 acc = make_float2(0.f, 0.f);
  int i = beg;
  for (; i + 1 < end; i += 2) {
    int s0 = esorted[i], s1 = esorted[i + 1];
    float2 k0 = ((const float2*)(K + (size_t)s0 * DIM))[lane];
    float2 v0 = ((const float2*)(V + (size_t)s0 * DIM))[lane];
    float2 k1 = ((const float2*)(K + (size_t)s1 * DIM))[lane];
    float2 v1 = ((const float2*)(V + (size_t)s1 * DIM))[lane];
    float sa = q.x * k0.x + q.y * k0.y;
    sa += __shfl_xor(sa, 1); sa += __shfl_xor(sa, 2); sa += __shfl_xor(sa, 4);
    float sb = q.x * k1.x + q.y * k1.y;
    sb += __shfl_xor(sb, 1); sb += __shfl_xor(sb, 2); sb += __shfl_xor(sb, 4);
    {
      float mn = fmaxf(m, sa);
      float sc = expf(m - mn), w = expf(sa - mn);
      den = den * sc + w;
      acc.x = acc.x * sc + w * v0.x;
      acc.y = acc.y * sc + w * v0.y;
      m = mn;
    }
    {
      float mn = fmaxf(m, sb);
      float sc = expf(m - mn), w = expf(sb - mn);
      den = den * sc + w;
      acc.x = acc.x * sc + w * v1.x;
      acc.y = acc.y * sc + w * v1.y;
      m = mn;
    }
  }
  if (i < end) {
    int s0 = esorted[i];
    float2 k0 = ((const float2*)(K + (size_t)s0 * DIM))[lane];
    float2 v0 = ((const float2*)(V + (size_t)s0 * DIM))[lane];
    float sa = q.x * k0.x + q.y * k0.y;
    sa += __shfl_xor(sa, 1); sa += __shfl_xor(sa, 2); sa += __shfl_xor(sa, 4);
    float mn = fmaxf(m, sa);
    float sc = expf(m - mn), w = expf(sa - mn);
    den = den * sc + w;
    acc.x = acc.x * sc + w * v0.x;
    acc.y = acc.y * sc + w * v0.y;
    m = mn;
  }
  float inv = 1.f / (den + 1e-16f);
  ((float2*)(att + (size_t)wid * DIM))[lane] = make_float2(acc.x * inv, acc.y * inv);
}

// ---------- K5/K6b: out = LN((a+b)/2)*g + be (+ optional bf16 copy) ----------
__global__ __launch_bounds__(256) void add_ln_kernel(
    const float* __restrict__ a, const float* __restrict__ b,
    const float* __restrict__ g, const float* __restrict__ be,
    float* __restrict__ out, short* __restrict__ ybf, int nrows) {
  int wave = (blockIdx.x * 256 + threadIdx.x) >> 6;
  int lane = threadIdx.x & 63;
  if (wave >= nrows) return;
  float2 av = ((const float2*)a)[(size_t)wave * 64 + lane];
  float2 bv = ((const float2*)b)[(size_t)wave * 64 + lane];
  float y0 = (av.x + bv.x) * 0.5f, y1 = (av.y + bv.y) * 0.5f;
  float s = y0 + y1;
  #pragma unroll
  for (int off = 32; off; off >>= 1) s += __shfl_xor(s, off);
  float mean = s * (1.0f / 128.0f);
  float d0 = y0 - mean, d1 = y1 - mean;
  float v = d0 * d0 + d1 * d1;
  #pragma unroll
  for (int off = 32; off; off >>= 1) v += __shfl_xor(v, off);
  float rstd = 1.0f / sqrtf(v * (1.0f / 128.0f) + 1e-5f);
  float2 gv = ((const float2*)g)[lane];
  float2 bev = ((const float2*)be)[lane];
  float2 o;
  o.x = gv.x * d0 * rstd + bev.x;
  o.y = gv.y * d1 * rstd + bev.y;
  ((float2*)out)[(size_t)wave * 64 + lane] = o;
  if (ybf) {
    unsigned pk = (unsigned short)f2bf(o.x) | ((unsigned)(unsigned short)f2bf(o.y) << 16);
    ((unsigned*)ybf)[(size_t)wave * 64 + lane] = pk;
  }
}

// ---------- K6: bf16-MFMA fused FFN, block-shared B via double-buffered LDS ----
// R11 diagnosis: R9==R10 to 0.03% despite conflict/barrier fixes => bottleneck
// was per-wave B-operand latency: every wave re-streamed 256KB of W from L2
// per-lane (16 lines/instr), serialized each iteration, ~12 waves/CU, nothing
// to hide it. Fix: weights pre-laid FRAGMENT-MAJOR (convw) so each iteration's
// 16KB B-chunk is contiguous; block stages it once into double-buffered LDS
// (reg-staged, load-early/write-late); all B reads become linear conflict-free
// ds_read_b128. MFMA order unchanged => bitwise-identical output (absmax
// must stay exactly 0.015625).
__global__ __launch_bounds__(256) void ffn_mfma_kernel(
    const short* __restrict__ Ybf, const short* __restrict__ W1F,
    const float* __restrict__ b1, const short* __restrict__ W2F,
    const float* __restrict__ b2, float* __restrict__ ff, int nrows) {
  __shared__ short Bsm[2][8192];     // 32KB: [buf][W1 chunk 4096 | W2 chunk 4096]
  __shared__ float Hlds[4][16 * 36]; // 9216B, per-wave H repack region
  const int tid = threadIdx.x;
  const int w = tid >> 6, lane = tid & 63;
  const int a = lane >> 4, c = lane & 15;
  const int rowbase = blockIdx.x * 64 + w * 16;
  float* Hw = Hlds[w];

  // A-frags for this wave's 16 rows (persist in registers)
  short8 af[4];
  {
    int r = rowbase + c;
    if (r < nrows) {
      const short* yp = Ybf + (size_t)r * 128 + a * 8;
      #pragma unroll
      for (int kc = 0; kc < 4; ++kc)
        af[kc] = *(const short8*)(yp + kc * 32);
    } else {
      short8 z = {0, 0, 0, 0, 0, 0, 0, 0};
      #pragma unroll
      for (int kc = 0; kc < 4; ++kc) af[kc] = z;
    }
  }

  // prologue: stage chunk 0 into buffer 0 (coalesced 16B loads, linear LDS)
  {
    short8 t0 = *(const short8*)(W1F + tid * 8);
    short8 t1 = *(const short8*)(W1F + 2048 + tid * 8);
    short8 t2 = *(const short8*)(W2F + tid * 8);
    short8 t3 = *(const short8*)(W2F + 2048 + tid * 8);
    *(short8*)(&Bsm[0][tid * 8])        = t0;
    *(short8*)(&Bsm[0][2048 + tid * 8]) = t1;
    *(short8*)(&Bsm[0][4096 + tid * 8]) = t2;
    *(short8*)(&Bsm[0][6144 + tid * 8]) = t3;
  }
  __syncthreads();

  f32x4 acc2[8];
  #pragma unroll
  for (int i = 0; i < 8; ++i) acc2[i] = (f32x4){0.f, 0.f, 0.f, 0.f};

  int cb = 0;
  for (int hc = 0; hc < 16; ++hc) {
    // issue next chunk's global loads EARLY (latency hides under compute)
    short8 s0, s1, s2, s3;
    if (hc < 15) {
      const short* p1 = W1F + (hc + 1) * 4096;
      const short* p2 = W2F + (hc + 1) * 4096;
      s0 = *(const short8*)(p1 + tid * 8);
      s1 = *(const short8*)(p1 + 2048 + tid * 8);
      s2 = *(const short8*)(p2 + tid * 8);
      s3 = *(const short8*)(p2 + 2048 + tid * 8);
    }
    const short* B1 = &Bsm[cb][0];
    const short* B2 = &Bsm[cb][4096];
    // GEMM1: H chunk (32 cols) from LDS B-frags (linear, conflict-free)
    f32x4 acc1[2];
    acc1[0] = (f32x4){0.f, 0.f, 0.f, 0.f};
    acc1[1] = (f32x4){0.f, 0.f, 0.f, 0.f};
    #pragma unroll
    for (int t = 0; t < 2; ++t) {
      #pragma unroll
      for (int kc = 0; kc < 4; ++kc) {
        short8 bfr = *(const short8*)(B1 + ((t * 4 + kc) << 9) + lane * 8);
        acc1[t] = __builtin_amdgcn_mfma_f32_16x16x32_bf16(af[kc], bfr, acc1[t], 0, 0, 0);
      }
    }
    // bias + relu -> per-wave LDS repack (stride 36: write 2-way=free, read clean)
    #pragma unroll
    for (int t = 0; t < 2; ++t) {
      float b1v = b1[hc * 32 + t * 16 + c];
      #pragma unroll
      for (int r = 0; r < 4; ++r) {
        float hv = fmaxf(acc1[t][r] + b1v, 0.f);
        Hw[(4 * a + r) * 36 + t * 16 + c] = hv;
      }
    }
    asm volatile("s_waitcnt lgkmcnt(0)" ::: "memory");  // wave-internal RAW
    float4 h0 = *(const float4*)(Hw + c * 36 + a * 8);
    float4 h1 = *(const float4*)(Hw + c * 36 + a * 8 + 4);
    short8 a2;
    a2[0] = f2bf(h0.x); a2[1] = f2bf(h0.y); a2[2] = f2bf(h0.z); a2[3] = f2bf(h0.w);
    a2[4] = f2bf(h1.x); a2[5] = f2bf(h1.y); a2[6] = f2bf(h1.z); a2[7] = f2bf(h1.w);
    asm volatile("s_waitcnt lgkmcnt(0)" ::: "memory");  // WAR guard
    // GEMM2: accumulate into persistent 128-wide accumulator
    #pragma unroll
    for (int nt = 0; nt < 8; ++nt) {
      short8 bfr = *(const short8*)(B2 + (nt << 9) + lane * 8);
      acc2[nt] = __builtin_amdgcn_mfma_f32_16x16x32_bf16(a2, bfr, acc2[nt], 0, 0, 0);
    }
    // write staged regs into the other buffer, one barrier per iteration
    if (hc < 15) {
      int nb = cb ^ 1;
      *(short8*)(&Bsm[nb][tid * 8])        = s0;
      *(short8*)(&Bsm[nb][2048 + tid * 8]) = s1;
      *(short8*)(&Bsm[nb][4096 + tid * 8]) = s2;
      *(short8*)(&Bsm[nb][6144 + tid * 8]) = s3;
      __syncthreads();  // staging visible; prior reads of nb-buffer 2 barriers back
      cb = nb;
    }
  }
  #pragma unroll
  for (int nt = 0; nt < 8; ++nt) {
    float b2v = b2[nt * 16 + c];
    #pragma unroll
    for (int r = 0; r < 4; ++r) {
      int row = rowbase + 4 * a + r;
      if (row < nrows)
        ff[(size_t)row * 128 + nt * 16 + c] = acc2[nt][r] + b2v;
    }
  }
}

// ---------- K8: in-place scale of output ----------
__global__ __launch_bounds__(256) void scale_kernel(float4* __restrict__ out,
                                                    const float* __restrict__ scl,
                                                    int n4) {
  int t = blockIdx.x * 256 + threadIdx.x;
  if (t < n4) {
    float s = scl[0];
    float4 v = out[t];
    v.x *= s; v.y *= s; v.z *= s; v.w *= s;
    out[t] = v;
  }
}

extern "C" void kernel_launch(void* const* d_in, const int* in_sizes, int n_in,
                              void* d_out, int out_size, void* d_ws, size_t ws_size,
                              hipStream_t stream) {
  const float* x   = (const float*)d_in[0];
  const int*   ei  = (const int*)  d_in[1];
  const float* Wq  = (const float*)d_in[2];
  const float* Wk  = (const float*)d_in[3];
  const float* Wv  = (const float*)d_in[4];
  const float* W1  = (const float*)d_in[5];
  const float* b1  = (const float*)d_in[6];
  const float* W2  = (const float*)d_in[7];
  const float* b2  = (const float*)d_in[8];
  const float* g1  = (const float*)d_in[9];
  const float* be1 = (const float*)d_in[10];
  const float* g2  = (const float*)d_in[11];
  const float* be2 = (const float*)d_in[12];
  float* out = (float*)d_out;
  float* ws  = (float*)d_ws;

  const size_t ND = (size_t)N_NODES * DIM;  // 6,400,000 floats

  // ---- workspace layout (u32 units from ws base), total ~105.6 MB ----
  float* CR0    = ws;      // ws[0]
  float* SCL    = ws + 1;  // ws[1]
  int*   ROWPTR = (int*)(ws + 16);            // 50001 (+pad to 50016)
  int*   CUR    = (int*)(ws + 16 + 50016);    // 50000 (counts, then cursors)
  int*   ESORT  = CUR + 50000;                // 600000
  short* W1F    = (short*)(ws + 700032);      // 65536 shorts (fragment-major)
  short* W2F    = W1F + 65536;                // 65536 shorts (fragment-major)
  short* WqT    = W2F + 65536;                // 16384 shorts
  short* WkT    = WqT + 16384;                // 16384 shorts
  short* WvT    = WkT + 16384;                // 16384 shorts
  float* Q      = ws + 790144;                // 16B-aligned
  float* K      = Q + ND;
  float* V      = K + ND;
  float* ATT    = V + ND;
  short* YBF    = (short*)Q;  // alias: Q dead after attn_kernel
  float* Y      = K;          // alias: K dead after attn_kernel
  float* FF     = V;          // alias: V dead after attn_kernel

  // 0. weight transposes -> bf16 (tiny)
  convw_kernel<<<512, 256, 0, stream>>>(W1, W2, W1F, W2F);
  convqkv_kernel<<<192, 256, 0, stream>>>(Wq, Wk, Wv, WqT, WkT, WvT);
  // 1. cr0 from raw x rows 0..3
  cr_kernel<<<1, 128, 0, stream>>>(x, 0.0f, 0, nullptr, CR0);
  // 2. Q,K,V GEMMs — bf16 MFMA
  qkv_mfma_kernel<<<(N_NODES + 63) / 64, 256, 0, stream>>>(x, WqT, WkT, WvT, Q, K, V, N_NODES);
  // 3. CSR build: histogram -> scan -> scatter
  zero_int_kernel<<<(N_NODES + 255) / 256, 256, 0, stream>>>(CUR, N_NODES);
  count_kernel<<<(N_EDGES + 255) / 256, 256, 0, stream>>>(ei, CUR, N_EDGES);
  scan_kernel<<<1, 1024, 0, stream>>>(CUR, ROWPTR, N_NODES);
  scatter_kernel<<<(N_EDGES + 255) / 256, 256, 0, stream>>>(ei, CUR, ESORT, N_EDGES);
  // 4. fused attention: one wave per node, online softmax, no atomics
  attn_kernel<<<N_NODES / 4, 256, 0, stream>>>(ROWPTR, ESORT, Q, K, V, ATT);
  // 5. y = LN1((x+att)/2)  (+ bf16 copy for FFN, into dead Q region)
  add_ln_kernel<<<N_NODES / 4, 256, 0, stream>>>(x, ATT, g1, be1, Y, YBF, N_NODES);
  // 6. ff = FFN(y)  — bf16 MFMA, LDS-staged B
  ffn_mfma_kernel<<<(N_NODES + 63) / 64, 256, 0, stream>>>(YBF, W1F, b1, W2F, b2, FF, N_NODES);
  // 7. z = LN2((y+ff)/2) -> d_out
  add_ln_kernel<<<N_NODES / 4, 256, 0, stream>>>(Y, FF, g2, be2, out, nullptr, N_NODES);
  // 8. cr on z, scale factor -> SCL
  cr_kernel<<<1, 128, 0, stream>>>(out, 1.0f, 1, CR0, SCL);
  // 9. out *= scale
  scale_kernel<<<(int)(ND / 4 / 256), 256, 0, stream>>>((float4*)out, SCL, (int)(ND / 4));
}

// Round 14
// 361.309 us; speedup vs baseline: 3.6265x; 1.2999x over previous
//
#include <hip/hip_runtime.h>
#include <hip/hip_bf16.h>
#include <math.h>

#define N_NODES 50000
#define N_EDGES 600000
#define DIM     128
#define NHEAD   8
#define DHEAD   16
#define DFF     512

typedef __attribute__((ext_vector_type(8))) short short8;
typedef __attribute__((ext_vector_type(4))) float f32x4;

__device__ __forceinline__ short f2bf(float f) {
  __hip_bfloat16 h = __float2bfloat16(f);
  union { __hip_bfloat16 h; short s; } u; u.h = h; return u.s;
}

// ---------- K0/K7: cross-ratio from 4 rows of a [*,128] matrix ----------
__global__ __launch_bounds__(128) void cr_kernel(const float* __restrict__ x,
                                                 float addone, int mode,
                                                 const float* __restrict__ cr0p,
                                                 float* __restrict__ out) {
  __shared__ float red[4][2];
  const int t = threadIdx.x, lane = t & 63, w = t >> 6;
  float a = x[t], b = x[128 + t], c = x[256 + t], d = x[384 + t];
  float pac = a * c, pbd = b * d, pad = a * d, pbc = b * c;
  #pragma unroll
  for (int off = 32; off; off >>= 1) {
    pac += __shfl_xor(pac, off);
    pbd += __shfl_xor(pbd, off);
    pad += __shfl_xor(pad, off);
    pbc += __shfl_xor(pbc, off);
  }
  if (lane == 0) { red[0][w] = pac; red[1][w] = pbd; red[2][w] = pad; red[3][w] = pbc; }
  __syncthreads();
  if (t == 0) {
    float ac = red[0][0] + red[0][1] + addone;
    float bd = red[1][0] + red[1][1] + addone;
    float ad = red[2][0] + red[2][1] + addone;
    float bc = red[3][0] + red[3][1] + addone;
    float cr = ac * bd / (ad * bc + 1e-8f);
    if (mode == 0) {
      out[0] = cr;
    } else {
      float cr0 = cr0p[0];
      bool fin_cr  = (cr == cr)  && (fabsf(cr)  < __int_as_float(0x7f800000));
      bool fin_cr0 = (cr0 == cr0) && (fabsf(cr0) < __int_as_float(0x7f800000));
      bool valid = fin_cr && fin_cr0 && (fabsf(cr) > 1e-8f);
      float scale = 1.0f;
      if (valid) scale = sqrtf(sqrtf(fabsf(cr0 / cr)));
      out[0] = scale;
    }
  }
}

// ---------- weight convert, FRAGMENT-MAJOR layout for the staged FFN ----------
__global__ __launch_bounds__(256) void convw_kernel(
    const float* __restrict__ W1, const float* __restrict__ W2,
    short* __restrict__ W1F, short* __restrict__ W2F) {
  int o = blockIdx.x * 256 + threadIdx.x;  // 0..131071
  int q = o & 65535;
  int hc = q >> 12, r = q & 4095, f = r >> 9, l = (r >> 3) & 63, j = q & 7;
  int a = l >> 4, c = l & 15;
  if (o < 65536) {
    int t = f >> 2, kc = f & 3;
    int k = kc * 32 + a * 8 + j, n = hc * 32 + t * 16 + c;
    W1F[q] = f2bf(W1[(size_t)k * 512 + n]);
  } else {
    int nt = f;
    int k = hc * 32 + a * 8 + j, n = nt * 16 + c;
    W2F[q] = f2bf(W2[(size_t)k * 128 + n]);
  }
}

// ---------- Wq/Wk/Wv transpose + bf16 convert: each [128][128] ----------
__global__ __launch_bounds__(256) void convqkv_kernel(
    const float* __restrict__ Wq, const float* __restrict__ Wk,
    const float* __restrict__ Wv, short* __restrict__ WqT,
    short* __restrict__ WkT, short* __restrict__ WvT) {
  int t = blockIdx.x * 256 + threadIdx.x;  // 0..49151
  int m = t >> 14, i = t & 16383;
  int n = i >> 7, k = i & 127;             // WT[n][k] = W[k][n]
  const float* W = (m == 0) ? Wq : (m == 1) ? Wk : Wv;
  short*      WT = (m == 0) ? WqT : (m == 1) ? WkT : WvT;
  WT[i] = f2bf(W[(size_t)k * 128 + n]);
}

// ---------- K1: bf16-MFMA QKV GEMM; K,V stored bf16 (attn gathers halve) ----
__global__ __launch_bounds__(256) void qkv_mfma_kernel(
    const float* __restrict__ x, const short* __restrict__ WqT,
    const short* __restrict__ WkT, const short* __restrict__ WvT,
    float* __restrict__ Qo, short* __restrict__ Kb, short* __restrict__ Vb,
    int nrows) {
  const int tid = threadIdx.x;
  const int w = tid >> 6, lane = tid & 63;
  const int a = lane >> 4, c = lane & 15;
  const int rowbase = blockIdx.x * 64 + w * 16;

  short8 af[4];
  {
    int r = rowbase + c;
    if (r < nrows) {
      const float* xp = x + (size_t)r * 128 + a * 8;
      #pragma unroll
      for (int kc = 0; kc < 4; ++kc) {
        float4 x0 = *(const float4*)(xp + kc * 32);
        float4 x1 = *(const float4*)(xp + kc * 32 + 4);
        short8 v;
        v[0] = f2bf(x0.x); v[1] = f2bf(x0.y); v[2] = f2bf(x0.z); v[3] = f2bf(x0.w);
        v[4] = f2bf(x1.x); v[5] = f2bf(x1.y); v[6] = f2bf(x1.z); v[7] = f2bf(x1.w);
        af[kc] = v;
      }
    } else {
      short8 z = {0, 0, 0, 0, 0, 0, 0, 0};
      #pragma unroll
      for (int kc = 0; kc < 4; ++kc) af[kc] = z;
    }
  }

  #pragma unroll
  for (int m = 0; m < 3; ++m) {
    const short* WT = (m == 0) ? WqT : (m == 1) ? WkT : WvT;
    f32x4 acc[8];
    #pragma unroll
    for (int nt = 0; nt < 8; ++nt) acc[nt] = (f32x4){0.f, 0.f, 0.f, 0.f};
    #pragma unroll
    for (int kc = 0; kc < 4; ++kc) {
      #pragma unroll
      for (int nt = 0; nt < 8; ++nt) {
        short8 bfr = *(const short8*)(WT + (size_t)(nt * 16 + c) * 128 + kc * 32 + a * 8);
        acc[nt] = __builtin_amdgcn_mfma_f32_16x16x32_bf16(af[kc], bfr, acc[nt], 0, 0, 0);
      }
    }
    if (m == 0) {
      #pragma unroll
      for (int nt = 0; nt < 8; ++nt) {
        #pragma unroll
        for (int rr = 0; rr < 4; ++rr) {
          int row = rowbase + 4 * a + rr;
          if (row < nrows)
            Qo[(size_t)row * 128 + nt * 16 + c] = acc[nt][rr];
        }
      }
    } else {
      short* Ob = (m == 1) ? Kb : Vb;
      #pragma unroll
      for (int nt = 0; nt < 8; ++nt) {
        #pragma unroll
        for (int rr = 0; rr < 4; ++rr) {
          int row = rowbase + 4 * a + rr;
          if (row < nrows)
            Ob[(size_t)row * 128 + nt * 16 + c] = f2bf(acc[nt][rr]);
        }
      }
    }
  }
}

// ---------- CSR build: zero counts ----------
__global__ __launch_bounds__(256) void zero_int_kernel(int* __restrict__ p, int n) {
  int t = blockIdx.x * 256 + threadIdx.x;
  if (t < n) p[t] = 0;
}

// ---------- CSR build: in-degree histogram ----------
__global__ __launch_bounds__(256) void count_kernel(const int* __restrict__ ei,
                                                    int* __restrict__ cnt, int nE) {
  int t = blockIdx.x * 256 + threadIdx.x;
  if (t < nE) atomicAdd(&cnt[ei[nE + t]], 1);
}

// ---------- CSR build: two-level scan (replaces 89.8us serial 1-block scan)
// level 1: per-block local exclusive scan + block totals
__global__ __launch_bounds__(1024) void blockscan_kernel(
    const int* __restrict__ cnt, int* __restrict__ loc,
    int* __restrict__ part, int n) {
  __shared__ int sdata[1024];
  const int tid = threadIdx.x;
  int i = blockIdx.x * 1024 + tid;
  int v = (i < n) ? cnt[i] : 0;
  sdata[tid] = v;
  __syncthreads();
  #pragma unroll
  for (int off = 1; off < 1024; off <<= 1) {
    int t = (tid >= off) ? sdata[tid - off] : 0;
    __syncthreads();
    sdata[tid] += t;
    __syncthreads();
  }
  if (i < n) loc[i] = sdata[tid] - v;  // exclusive within block
  if (tid == 1023) part[blockIdx.x] = sdata[1023];
}

// level 2: single-wave shfl scan of the 49 block totals
__global__ __launch_bounds__(64) void partscan_kernel(int* __restrict__ part, int nb) {
  int l = threadIdx.x;
  int orig = (l < nb) ? part[l] : 0;
  int v = orig;
  #pragma unroll
  for (int off = 1; off < 64; off <<= 1) {
    int t = __shfl_up(v, off);
    if (l >= off) v += t;
  }
  if (l < nb) part[l] = v - orig;      // exclusive
  int tot = __shfl(v, nb - 1);         // inclusive at last valid lane
  if (l == 0) part[nb] = tot;
}

// level 3: apply block offsets; write rowptr and cursor copy
__global__ __launch_bounds__(1024) void scanapply_kernel(
    const int* __restrict__ loc, const int* __restrict__ part,
    int* __restrict__ rowptr, int* __restrict__ cur, int n, int nb) {
  int i = blockIdx.x * 1024 + threadIdx.x;
  if (i < n) {
    int e = loc[i] + part[blockIdx.x];
    rowptr[i] = e;
    cur[i]    = e;
  }
  if (i == 0) rowptr[n] = part[nb];
}

// ---------- CSR build: scatter src ids into dst-sorted order ----------
__global__ __launch_bounds__(256) void scatter_kernel(const int* __restrict__ ei,
                                                      int* __restrict__ cur,
                                                      int* __restrict__ esorted, int nE) {
  int t = blockIdx.x * 256 + threadIdx.x;
  if (t < nE) {
    int d = ei[nE + t];
    int p = atomicAdd(&cur[d], 1);
    esorted[p] = ei[t];
  }
}

// ---------- K2-4 fused: per-node online-softmax attention over CSR ----------
// K/V gathered as bf16 (uint-packed pairs) -- halves the 614MB/dispatch
// gather traffic that had attn at 45% HBM-equivalent BW. Q stays f32.
__global__ __launch_bounds__(256) void attn_kernel(
    const int* __restrict__ rowptr, const int* __restrict__ esorted,
    const float* __restrict__ Q, const short* __restrict__ Kb,
    const short* __restrict__ Vb, float* __restrict__ att) {
  int wid  = (blockIdx.x * 256 + threadIdx.x) >> 6;
  int lane = threadIdx.x & 63;
  if (wid >= N_NODES) return;
  int beg = rowptr[wid], end = rowptr[wid + 1];
  float2 q = ((const float2*)(Q + (size_t)wid * DIM))[lane];
  q.x *= 0.25f; q.y *= 0.25f;  // 1/sqrt(16)
  float m = -__int_as_float(0x7f800000);  // -inf
  float den = 0.f;
  float2 acc = make_float2(0.f, 0.f);
  int i = beg;
  for (; i + 1 < end; i += 2) {
    int s0 = esorted[i], s1 = esorted[i + 1];
    unsigned ku0 = ((const unsigned*)(Kb + (size_t)s0 * DIM))[lane];
    unsigned vu0 = ((const unsigned*)(Vb + (size_t)s0 * DIM))[lane];
    unsigned ku1 = ((const unsigned*)(Kb + (size_t)s1 * DIM))[lane];
    unsigned vu1 = ((const unsigned*)(Vb + (size_t)s1 * DIM))[lane];
    float sa = q.x * __uint_as_float(ku0 << 16) + q.y * __uint_as_float(ku0 & 0xffff0000u);
    sa += __shfl_xor(sa, 1); sa += __shfl_xor(sa, 2); sa += __shfl_xor(sa, 4);
    float sb = q.x * __uint_as_float(ku1 << 16) + q.y * __uint_as_float(ku1 & 0xffff0000u);
    sb += __shfl_xor(sb, 1); sb += __shfl_xor(sb, 2); sb += __shfl_xor(sb, 4);
    {
      float mn = fmaxf(m, sa);
      float sc = expf(m - mn), w = expf(sa - mn);
      den = den * sc + w;
      acc.x = acc.x * sc + w * __uint_as_float(vu0 << 16);
      acc.y = acc.y * sc + w * __uint_as_float(vu0 & 0xffff0000u);
      m = mn;
    }
    {
      float mn = fmaxf(m, sb);
      float sc = expf(m - mn), w = expf(sb - mn);
      den = den * sc + w;
      acc.x = acc.x * sc + w * __uint_as_float(vu1 << 16);
      acc.y = acc.y * sc + w * __uint_as_float(vu1 & 0xffff0000u);
      m = mn;
    }
  }
  if (i < end) {
    int s0 = esorted[i];
    unsigned ku0 = ((const unsigned*)(Kb + (size_t)s0 * DIM))[lane];
    unsigned vu0 = ((const unsigned*)(Vb + (size_t)s0 * DIM))[lane];
    float sa = q.x * __uint_as_float(ku0 << 16) + q.y * __uint_as_float(ku0 & 0xffff0000u);
    sa += __shfl_xor(sa, 1); sa += __shfl_xor(sa, 2); sa += __shfl_xor(sa, 4);
    float mn = fmaxf(m, sa);
    float sc = expf(m - mn), w = expf(sa - mn);
    den = den * sc + w;
    acc.x = acc.x * sc + w * __uint_as_float(vu0 << 16);
    acc.y = acc.y * sc + w * __uint_as_float(vu0 & 0xffff0000u);
    m = mn;
  }
  float inv = 1.f / (den + 1e-16f);
  ((float2*)(att + (size_t)wid * DIM))[lane] = make_float2(acc.x * inv, acc.y * inv);
}

// ---------- K5/K6b: out = LN((a+b)/2)*g + be (+ optional bf16 copy) ----------
__global__ __launch_bounds__(256) void add_ln_kernel(
    const float* __restrict__ a, const float* __restrict__ b,
    const float* __restrict__ g, const float* __restrict__ be,
    float* __restrict__ out, short* __restrict__ ybf, int nrows) {
  int wave = (blockIdx.x * 256 + threadIdx.x) >> 6;
  int lane = threadIdx.x & 63;
  if (wave >= nrows) return;
  float2 av = ((const float2*)a)[(size_t)wave * 64 + lane];
  float2 bv = ((const float2*)b)[(size_t)wave * 64 + lane];
  float y0 = (av.x + bv.x) * 0.5f, y1 = (av.y + bv.y) * 0.5f;
  float s = y0 + y1;
  #pragma unroll
  for (int off = 32; off; off >>= 1) s += __shfl_xor(s, off);
  float mean = s * (1.0f / 128.0f);
  float d0 = y0 - mean, d1 = y1 - mean;
  float v = d0 * d0 + d1 * d1;
  #pragma unroll
  for (int off = 32; off; off >>= 1) v += __shfl_xor(v, off);
  float rstd = 1.0f / sqrtf(v * (1.0f / 128.0f) + 1e-5f);
  float2 gv = ((const float2*)g)[lane];
  float2 bev = ((const float2*)be)[lane];
  float2 o;
  o.x = gv.x * d0 * rstd + bev.x;
  o.y = gv.y * d1 * rstd + bev.y;
  ((float2*)out)[(size_t)wave * 64 + lane] = o;
  if (ybf) {
    unsigned pk = (unsigned short)f2bf(o.x) | ((unsigned)(unsigned short)f2bf(o.y) << 16);
    ((unsigned*)ybf)[(size_t)wave * 64 + lane] = pk;
  }
}

// ---------- K6: bf16-MFMA fused FFN, block-shared B via double-buffered LDS ----
__global__ __launch_bounds__(256) void ffn_mfma_kernel(
    const short* __restrict__ Ybf, const short* __restrict__ W1F,
    const float* __restrict__ b1, const short* __restrict__ W2F,
    const float* __restrict__ b2, float* __restrict__ ff, int nrows) {
  __shared__ short Bsm[2][8192];     // 32KB: [buf][W1 chunk 4096 | W2 chunk 4096]
  __shared__ float Hlds[4][16 * 36]; // 9216B, per-wave H repack region
  const int tid = threadIdx.x;
  const int w = tid >> 6, lane = tid & 63;
  const int a = lane >> 4, c = lane & 15;
  const int rowbase = blockIdx.x * 64 + w * 16;
  float* Hw = Hlds[w];

  short8 af[4];
  {
    int r = rowbase + c;
    if (r < nrows) {
      const short* yp = Ybf + (size_t)r * 128 + a * 8;
      #pragma unroll
      for (int kc = 0; kc < 4; ++kc)
        af[kc] = *(const short8*)(yp + kc * 32);
    } else {
      short8 z = {0, 0, 0, 0, 0, 0, 0, 0};
      #pragma unroll
      for (int kc = 0; kc < 4; ++kc) af[kc] = z;
    }
  }

  {
    short8 t0 = *(const short8*)(W1F + tid * 8);
    short8 t1 = *(const short8*)(W1F + 2048 + tid * 8);
    short8 t2 = *(const short8*)(W2F + tid * 8);
    short8 t3 = *(const short8*)(W2F + 2048 + tid * 8);
    *(short8*)(&Bsm[0][tid * 8])        = t0;
    *(short8*)(&Bsm[0][2048 + tid * 8]) = t1;
    *(short8*)(&Bsm[0][4096 + tid * 8]) = t2;
    *(short8*)(&Bsm[0][6144 + tid * 8]) = t3;
  }
  __syncthreads();

  f32x4 acc2[8];
  #pragma unroll
  for (int i = 0; i < 8; ++i) acc2[i] = (f32x4){0.f, 0.f, 0.f, 0.f};

  int cb = 0;
  for (int hc = 0; hc < 16; ++hc) {
    short8 s0, s1, s2, s3;
    if (hc < 15) {
      const short* p1 = W1F + (hc + 1) * 4096;
      const short* p2 = W2F + (hc + 1) * 4096;
      s0 = *(const short8*)(p1 + tid * 8);
      s1 = *(const short8*)(p1 + 2048 + tid * 8);
      s2 = *(const short8*)(p2 + tid * 8);
      s3 = *(const short8*)(p2 + 2048 + tid * 8);
    }
    const short* B1 = &Bsm[cb][0];
    const short* B2 = &Bsm[cb][4096];
    f32x4 acc1[2];
    acc1[0] = (f32x4){0.f, 0.f, 0.f, 0.f};
    acc1[1] = (f32x4){0.f, 0.f, 0.f, 0.f};
    #pragma unroll
    for (int t = 0; t < 2; ++t) {
      #pragma unroll
      for (int kc = 0; kc < 4; ++kc) {
        short8 bfr = *(const short8*)(B1 + ((t * 4 + kc) << 9) + lane * 8);
        acc1[t] = __builtin_amdgcn_mfma_f32_16x16x32_bf16(af[kc], bfr, acc1[t], 0, 0, 0);
      }
    }
    #pragma unroll
    for (int t = 0; t < 2; ++t) {
      float b1v = b1[hc * 32 + t * 16 + c];
      #pragma unroll
      for (int r = 0; r < 4; ++r) {
        float hv = fmaxf(acc1[t][r] + b1v, 0.f);
        Hw[(4 * a + r) * 36 + t * 16 + c] = hv;
      }
    }
    asm volatile("s_waitcnt lgkmcnt(0)" ::: "memory");
    float4 h0 = *(const float4*)(Hw + c * 36 + a * 8);
    float4 h1 = *(const float4*)(Hw + c * 36 + a * 8 + 4);
    short8 a2;
    a2[0] = f2bf(h0.x); a2[1] = f2bf(h0.y); a2[2] = f2bf(h0.z); a2[3] = f2bf(h0.w);
    a2[4] = f2bf(h1.x); a2[5] = f2bf(h1.y); a2[6] = f2bf(h1.z); a2[7] = f2bf(h1.w);
    asm volatile("s_waitcnt lgkmcnt(0)" ::: "memory");
    #pragma unroll
    for (int nt = 0; nt < 8; ++nt) {
      short8 bfr = *(const short8*)(B2 + (nt << 9) + lane * 8);
      acc2[nt] = __builtin_amdgcn_mfma_f32_16x16x32_bf16(a2, bfr, acc2[nt], 0, 0, 0);
    }
    if (hc < 15) {
      int nb = cb ^ 1;
      *(short8*)(&Bsm[nb][tid * 8])        = s0;
      *(short8*)(&Bsm[nb][2048 + tid * 8]) = s1;
      *(short8*)(&Bsm[nb][4096 + tid * 8]) = s2;
      *(short8*)(&Bsm[nb][6144 + tid * 8]) = s3;
      __syncthreads();
      cb = nb;
    }
  }
  #pragma unroll
  for (int nt = 0; nt < 8; ++nt) {
    float b2v = b2[nt * 16 + c];
    #pragma unroll
    for (int r = 0; r < 4; ++r) {
      int row = rowbase + 4 * a + r;
      if (row < nrows)
        ff[(size_t)row * 128 + nt * 16 + c] = acc2[nt][r] + b2v;
    }
  }
}

// ---------- K8: in-place scale of output ----------
__global__ __launch_bounds__(256) void scale_kernel(float4* __restrict__ out,
                                                    const float* __restrict__ scl,
                                                    int n4) {
  int t = blockIdx.x * 256 + threadIdx.x;
  if (t < n4) {
    float s = scl[0];
    float4 v = out[t];
    v.x *= s; v.y *= s; v.z *= s; v.w *= s;
    out[t] = v;
  }
}

extern "C" void kernel_launch(void* const* d_in, const int* in_sizes, int n_in,
                              void* d_out, int out_size, void* d_ws, size_t ws_size,
                              hipStream_t stream) {
  const float* x   = (const float*)d_in[0];
  const int*   ei  = (const int*)  d_in[1];
  const float* Wq  = (const float*)d_in[2];
  const float* Wk  = (const float*)d_in[3];
  const float* Wv  = (const float*)d_in[4];
  const float* W1  = (const float*)d_in[5];
  const float* b1  = (const float*)d_in[6];
  const float* W2  = (const float*)d_in[7];
  const float* b2  = (const float*)d_in[8];
  const float* g1  = (const float*)d_in[9];
  const float* be1 = (const float*)d_in[10];
  const float* g2  = (const float*)d_in[11];
  const float* be2 = (const float*)d_in[12];
  float* out = (float*)d_out;
  float* ws  = (float*)d_ws;

  const size_t ND = (size_t)N_NODES * DIM;  // 6,400,000 floats
  const int NB = (N_NODES + 1023) / 1024;   // 49 scan blocks

  // ---- workspace layout (u32 units from ws base), total ~105.6 MB ----
  float* CR0    = ws;      // ws[0]
  float* SCL    = ws + 1;  // ws[1]
  int*   ROWPTR = (int*)(ws + 16);            // 50001 (+pad to 50016)
  int*   CUR    = (int*)(ws + 16 + 50016);    // 50000 (counts, then cursors)
  int*   ESORT  = CUR + 50000;                // 600000
  int*   LOC    = ESORT;                      // alias: dead before scatter writes
  int*   PART   = ESORT + 51200;              // 50 ints, still inside ESORT region
  short* W1F    = (short*)(ws + 700032);      // 65536 shorts (fragment-major)
  short* W2F    = W1F + 65536;                // 65536 shorts (fragment-major)
  short* WqT    = W2F + 65536;                // 16384 shorts
  short* WkT    = WqT + 16384;                // 16384 shorts
  short* WvT    = WkT + 16384;                // 16384 shorts
  float* Q      = ws + 790144;                // 16B-aligned
  float* K      = Q + ND;                     // region reserved; holds Kb (bf16)
  float* V      = K + ND;                     // region reserved; holds Vb (bf16)
  float* ATT    = V + ND;
  short* Kbf    = (short*)K;
  short* Vbf    = (short*)V;
  short* YBF    = (short*)Q;  // alias: Q dead after attn_kernel
  float* Y      = K;          // alias: K region dead after attn_kernel
  float* FF     = V;          // alias: V region dead after attn_kernel

  // 0. weight transposes -> bf16 (tiny)
  convw_kernel<<<512, 256, 0, stream>>>(W1, W2, W1F, W2F);
  convqkv_kernel<<<192, 256, 0, stream>>>(Wq, Wk, Wv, WqT, WkT, WvT);
  // 1. cr0 from raw x rows 0..3
  cr_kernel<<<1, 128, 0, stream>>>(x, 0.0f, 0, nullptr, CR0);
  // 2. Q,K,V GEMMs — bf16 MFMA; K,V emitted as bf16
  qkv_mfma_kernel<<<(N_NODES + 63) / 64, 256, 0, stream>>>(x, WqT, WkT, WvT, Q, Kbf, Vbf, N_NODES);
  // 3. CSR build: histogram -> two-level scan -> scatter
  zero_int_kernel<<<(N_NODES + 255) / 256, 256, 0, stream>>>(CUR, N_NODES);
  count_kernel<<<(N_EDGES + 255) / 256, 256, 0, stream>>>(ei, CUR, N_EDGES);
  blockscan_kernel<<<NB, 1024, 0, stream>>>(CUR, LOC, PART, N_NODES);
  partscan_kernel<<<1, 64, 0, stream>>>(PART, NB);
  scanapply_kernel<<<NB, 1024, 0, stream>>>(LOC, PART, ROWPTR, CUR, N_NODES, NB);
  scatter_kernel<<<(N_EDGES + 255) / 256, 256, 0, stream>>>(ei, CUR, ESORT, N_EDGES);
  // 4. fused attention: one wave per node, online softmax, bf16 K/V gathers
  attn_kernel<<<N_NODES / 4, 256, 0, stream>>>(ROWPTR, ESORT, Q, Kbf, Vbf, ATT);
  // 5. y = LN1((x+att)/2)  (+ bf16 copy for FFN, into dead Q region)
  add_ln_kernel<<<N_NODES / 4, 256, 0, stream>>>(x, ATT, g1, be1, Y, YBF, N_NODES);
  // 6. ff = FFN(y)  — bf16 MFMA, LDS-staged B
  ffn_mfma_kernel<<<(N_NODES + 63) / 64, 256, 0, stream>>>(YBF, W1F, b1, W2F, b2, FF, N_NODES);
  // 7. z = LN2((y+ff)/2) -> d_out
  add_ln_kernel<<<N_NODES / 4, 256, 0, stream>>>(Y, FF, g2, be2, out, nullptr, N_NODES);
  // 8. cr on z, scale factor -> SCL
  cr_kernel<<<1, 128, 0, stream>>>(out, 1.0f, 1, CR0, SCL);
  // 9. out *= scale
  scale_kernel<<<(int)(ND / 4 / 256), 256, 0, stream>>>((float4*)out, SCL, (int)(ND / 4));
}

// Round 16
// 326.024 us; speedup vs baseline: 4.0189x; 1.1082x over previous
//
#include <hip/hip_runtime.h>
#include <hip/hip_bf16.h>
#include <math.h>

#define N_NODES 50000
#define N_EDGES 600000
#define DIM     128
#define NHEAD   8
#define DHEAD   16
#define DFF     512

typedef __attribute__((ext_vector_type(8))) short short8;
typedef __attribute__((ext_vector_type(4))) float f32x4;

__device__ __forceinline__ short f2bf(float f) {
  __hip_bfloat16 h = __float2bfloat16(f);
  union { __hip_bfloat16 h; short s; } u; u.h = h; return u.s;
}

// ---------- K0/K7: cross-ratio from 4 rows of a [*,128] matrix ----------
__global__ __launch_bounds__(128) void cr_kernel(const float* __restrict__ x,
                                                 float addone, int mode,
                                                 const float* __restrict__ cr0p,
                                                 float* __restrict__ out) {
  __shared__ float red[4][2];
  const int t = threadIdx.x, lane = t & 63, w = t >> 6;
  float a = x[t], b = x[128 + t], c = x[256 + t], d = x[384 + t];
  float pac = a * c, pbd = b * d, pad = a * d, pbc = b * c;
  #pragma unroll
  for (int off = 32; off; off >>= 1) {
    pac += __shfl_xor(pac, off);
    pbd += __shfl_xor(pbd, off);
    pad += __shfl_xor(pad, off);
    pbc += __shfl_xor(pbc, off);
  }
  if (lane == 0) { red[0][w] = pac; red[1][w] = pbd; red[2][w] = pad; red[3][w] = pbc; }
  __syncthreads();
  if (t == 0) {
    float ac = red[0][0] + red[0][1] + addone;
    float bd = red[1][0] + red[1][1] + addone;
    float ad = red[2][0] + red[2][1] + addone;
    float bc = red[3][0] + red[3][1] + addone;
    float cr = ac * bd / (ad * bc + 1e-8f);
    if (mode == 0) {
      out[0] = cr;
    } else {
      float cr0 = cr0p[0];
      bool fin_cr  = (cr == cr)  && (fabsf(cr)  < __int_as_float(0x7f800000));
      bool fin_cr0 = (cr0 == cr0) && (fabsf(cr0) < __int_as_float(0x7f800000));
      bool valid = fin_cr && fin_cr0 && (fabsf(cr) > 1e-8f);
      float scale = 1.0f;
      if (valid) scale = sqrtf(sqrtf(fabsf(cr0 / cr)));
      out[0] = scale;
    }
  }
}

// ---------- weight convert, FRAGMENT-MAJOR layout for the staged FFN ----------
__global__ __launch_bounds__(256) void convw_kernel(
    const float* __restrict__ W1, const float* __restrict__ W2,
    short* __restrict__ W1F, short* __restrict__ W2F) {
  int o = blockIdx.x * 256 + threadIdx.x;  // 0..131071
  int q = o & 65535;
  int hc = q >> 12, r = q & 4095, f = r >> 9, l = (r >> 3) & 63, j = q & 7;
  int a = l >> 4, c = l & 15;
  if (o < 65536) {
    int t = f >> 2, kc = f & 3;
    int k = kc * 32 + a * 8 + j, n = hc * 32 + t * 16 + c;
    W1F[q] = f2bf(W1[(size_t)k * 512 + n]);
  } else {
    int nt = f;
    int k = hc * 32 + a * 8 + j, n = nt * 16 + c;
    W2F[q] = f2bf(W2[(size_t)k * 128 + n]);
  }
}

// ---------- Wq/Wk/Wv FRAGMENT-MAJOR bf16 convert (coalesced qkv B-loads)
// WF: [f:32 = nt*4+kc][lane:64][j:8] bf16; value = W[k][n],
//   k = kc*32 + (l>>4)*8 + j, n = nt*16 + (l&15).
// A wave's fragment load is a contiguous 1KB block (was 16 x 256B-strided
// lines via the [n][k] transpose layout -- same per-wave-latency pattern
// that R11's fragment-major fix removed from ffn).
__global__ __launch_bounds__(256) void convqkv_kernel(
    const float* __restrict__ Wq, const float* __restrict__ Wk,
    const float* __restrict__ Wv, short* __restrict__ WqF,
    short* __restrict__ WkF, short* __restrict__ WvF) {
  int t = blockIdx.x * 256 + threadIdx.x;  // 0..49151
  int m = t >> 14, i = t & 16383;
  int f = i >> 9, l = (i >> 3) & 63, j = i & 7;
  int nt = f >> 2, kc = f & 3;
  int a = l >> 4, c = l & 15;
  int k = kc * 32 + a * 8 + j, n = nt * 16 + c;
  const float* W = (m == 0) ? Wq : (m == 1) ? Wk : Wv;
  short*      WF = (m == 0) ? WqF : (m == 1) ? WkF : WvF;
  WF[i] = f2bf(W[(size_t)k * 128 + n]);
}

// ---------- K1: bf16-MFMA QKV GEMM; K,V stored bf16; frag-major B ----------
__global__ __launch_bounds__(256) void qkv_mfma_kernel(
    const float* __restrict__ x, const short* __restrict__ WqF,
    const short* __restrict__ WkF, const short* __restrict__ WvF,
    float* __restrict__ Qo, short* __restrict__ Kb, short* __restrict__ Vb,
    int nrows) {
  const int tid = threadIdx.x;
  const int w = tid >> 6, lane = tid & 63;
  const int a = lane >> 4, c = lane & 15;
  const int rowbase = blockIdx.x * 64 + w * 16;

  short8 af[4];
  {
    int r = rowbase + c;
    if (r < nrows) {
      const float* xp = x + (size_t)r * 128 + a * 8;
      #pragma unroll
      for (int kc = 0; kc < 4; ++kc) {
        float4 x0 = *(const float4*)(xp + kc * 32);
        float4 x1 = *(const float4*)(xp + kc * 32 + 4);
        short8 v;
        v[0] = f2bf(x0.x); v[1] = f2bf(x0.y); v[2] = f2bf(x0.z); v[3] = f2bf(x0.w);
        v[4] = f2bf(x1.x); v[5] = f2bf(x1.y); v[6] = f2bf(x1.z); v[7] = f2bf(x1.w);
        af[kc] = v;
      }
    } else {
      short8 z = {0, 0, 0, 0, 0, 0, 0, 0};
      #pragma unroll
      for (int kc = 0; kc < 4; ++kc) af[kc] = z;
    }
  }

  #pragma unroll
  for (int m = 0; m < 3; ++m) {
    const short* WF = (m == 0) ? WqF : (m == 1) ? WkF : WvF;
    f32x4 acc[8];
    #pragma unroll
    for (int nt = 0; nt < 8; ++nt) acc[nt] = (f32x4){0.f, 0.f, 0.f, 0.f};
    #pragma unroll
    for (int kc = 0; kc < 4; ++kc) {
      #pragma unroll
      for (int nt = 0; nt < 8; ++nt) {
        short8 bfr = *(const short8*)(WF + ((nt * 4 + kc) << 9) + lane * 8);
        acc[nt] = __builtin_amdgcn_mfma_f32_16x16x32_bf16(af[kc], bfr, acc[nt], 0, 0, 0);
      }
    }
    if (m == 0) {
      #pragma unroll
      for (int nt = 0; nt < 8; ++nt) {
        #pragma unroll
        for (int rr = 0; rr < 4; ++rr) {
          int row = rowbase + 4 * a + rr;
          if (row < nrows)
            Qo[(size_t)row * 128 + nt * 16 + c] = acc[nt][rr];
        }
      }
    } else {
      short* Ob = (m == 1) ? Kb : Vb;
      #pragma unroll
      for (int nt = 0; nt < 8; ++nt) {
        #pragma unroll
        for (int rr = 0; rr < 4; ++rr) {
          int row = rowbase + 4 * a + rr;
          if (row < nrows)
            Ob[(size_t)row * 128 + nt * 16 + c] = f2bf(acc[nt][rr]);
        }
      }
    }
  }
}

// ---------- CSR build: zero counts ----------
__global__ __launch_bounds__(256) void zero_int_kernel(int* __restrict__ p, int n) {
  int t = blockIdx.x * 256 + threadIdx.x;
  if (t < n) p[t] = 0;
}

// ---------- CSR build: in-degree histogram ----------
__global__ __launch_bounds__(256) void count_kernel(const int* __restrict__ ei,
                                                    int* __restrict__ cnt, int nE) {
  int t = blockIdx.x * 256 + threadIdx.x;
  if (t < nE) atomicAdd(&cnt[ei[nE + t]], 1);
}

// ---------- CSR build: two-level scan ----------
__global__ __launch_bounds__(1024) void blockscan_kernel(
    const int* __restrict__ cnt, int* __restrict__ loc,
    int* __restrict__ part, int n) {
  __shared__ int sdata[1024];
  const int tid = threadIdx.x;
  int i = blockIdx.x * 1024 + tid;
  int v = (i < n) ? cnt[i] : 0;
  sdata[tid] = v;
  __syncthreads();
  #pragma unroll
  for (int off = 1; off < 1024; off <<= 1) {
    int t = (tid >= off) ? sdata[tid - off] : 0;
    __syncthreads();
    sdata[tid] += t;
    __syncthreads();
  }
  if (i < n) loc[i] = sdata[tid] - v;  // exclusive within block
  if (tid == 1023) part[blockIdx.x] = sdata[1023];
}

__global__ __launch_bounds__(64) void partscan_kernel(int* __restrict__ part, int nb) {
  int l = threadIdx.x;
  int orig = (l < nb) ? part[l] : 0;
  int v = orig;
  #pragma unroll
  for (int off = 1; off < 64; off <<= 1) {
    int t = __shfl_up(v, off);
    if (l >= off) v += t;
  }
  if (l < nb) part[l] = v - orig;      // exclusive
  int tot = __shfl(v, nb - 1);         // inclusive at last valid lane
  if (l == 0) part[nb] = tot;
}

__global__ __launch_bounds__(1024) void scanapply_kernel(
    const int* __restrict__ loc, const int* __restrict__ part,
    int* __restrict__ rowptr, int* __restrict__ cur, int n, int nb) {
  int i = blockIdx.x * 1024 + threadIdx.x;
  if (i < n) {
    int e = loc[i] + part[blockIdx.x];
    rowptr[i] = e;
    cur[i]    = e;
  }
  if (i == 0) rowptr[n] = part[nb];
}

// ---------- CSR build: scatter src ids into dst-sorted order ----------
__global__ __launch_bounds__(256) void scatter_kernel(const int* __restrict__ ei,
                                                      int* __restrict__ cur,
                                                      int* __restrict__ esorted, int nE) {
  int t = blockIdx.x * 256 + threadIdx.x;
  if (t < nE) {
    int d = ei[nE + t];
    int p = atomicAdd(&cur[d], 1);
    esorted[p] = ei[t];
  }
}

// ---------- K2-4 fused: per-node online-softmax attention over CSR ----------
// Defer-max (T13, THR=11.5 in log2 ~ e^8) + log2-domain scores (log2e
// folded into Q scale; exp2 replaces exp). Common path per edge: sub, cmp,
// 1 exp2, 3 FMA -- was fmax + 2 expf + 5 rescale mults on the serial chain.
// attn was VALU-bound (84-87% VALUBusy) after R14 halved its bytes.
__global__ __launch_bounds__(256) void attn_kernel(
    const int* __restrict__ rowptr, const int* __restrict__ esorted,
    const float* __restrict__ Q, const short* __restrict__ Kb,
    const short* __restrict__ Vb, float* __restrict__ att) {
  int wid  = (blockIdx.x * 256 + threadIdx.x) >> 6;
  int lane = threadIdx.x & 63;
  if (wid >= N_NODES) return;
  int beg = rowptr[wid], end = rowptr[wid + 1];
  float2 q = ((const float2*)(Q + (size_t)wid * DIM))[lane];
  const float SCL2 = 0.25f * 1.442695040888963f;  // 1/sqrt(16) * log2(e)
  q.x *= SCL2; q.y *= SCL2;
  float m = -__int_as_float(0x7f800000);  // -inf (first edge takes rescale path)
  float den = 0.f;
  float2 acc = make_float2(0.f, 0.f);
  int i = beg;
  for (; i + 1 < end; i += 2) {
    int s0 = esorted[i], s1 = esorted[i + 1];
    unsigned ku0 = ((const unsigned*)(Kb + (size_t)s0 * DIM))[lane];
    unsigned vu0 = ((const unsigned*)(Vb + (size_t)s0 * DIM))[lane];
    unsigned ku1 = ((const unsigned*)(Kb + (size_t)s1 * DIM))[lane];
    unsigned vu1 = ((const unsigned*)(Vb + (size_t)s1 * DIM))[lane];
    float sa = q.x * __uint_as_float(ku0 << 16) + q.y * __uint_as_float(ku0 & 0xffff0000u);
    sa += __shfl_xor(sa, 1); sa += __shfl_xor(sa, 2); sa += __shfl_xor(sa, 4);
    float sb = q.x * __uint_as_float(ku1 << 16) + q.y * __uint_as_float(ku1 & 0xffff0000u);
    sb += __shfl_xor(sb, 1); sb += __shfl_xor(sb, 2); sb += __shfl_xor(sb, 4);
    {
      float v0x = __uint_as_float(vu0 << 16), v0y = __uint_as_float(vu0 & 0xffff0000u);
      float d0 = sa - m;
      if (d0 > 11.5f) {                 // rare: rescale to new max
        float sc = exp2f(-d0);          // m=-inf -> 0
        den = den * sc + 1.0f;
        acc.x = acc.x * sc + v0x;
        acc.y = acc.y * sc + v0y;
        m = sa;
      } else {                          // common: no rescale
        float wgt = exp2f(d0);          // bounded by 2^11.5
        den += wgt;
        acc.x += wgt * v0x;
        acc.y += wgt * v0y;
      }
    }
    {
      float v1x = __uint_as_float(vu1 << 16), v1y = __uint_as_float(vu1 & 0xffff0000u);
      float d1 = sb - m;
      if (d1 > 11.5f) {
        float sc = exp2f(-d1);
        den = den * sc + 1.0f;
        acc.x = acc.x * sc + v1x;
        acc.y = acc.y * sc + v1y;
        m = sb;
      } else {
        float wgt = exp2f(d1);
        den += wgt;
        acc.x += wgt * v1x;
        acc.y += wgt * v1y;
      }
    }
  }
  if (i < end) {
    int s0 = esorted[i];
    unsigned ku0 = ((const unsigned*)(Kb + (size_t)s0 * DIM))[lane];
    unsigned vu0 = ((const unsigned*)(Vb + (size_t)s0 * DIM))[lane];
    float sa = q.x * __uint_as_float(ku0 << 16) + q.y * __uint_as_float(ku0 & 0xffff0000u);
    sa += __shfl_xor(sa, 1); sa += __shfl_xor(sa, 2); sa += __shfl_xor(sa, 4);
    float v0x = __uint_as_float(vu0 << 16), v0y = __uint_as_float(vu0 & 0xffff0000u);
    float d0 = sa - m;
    if (d0 > 11.5f) {
      float sc = exp2f(-d0);
      den = den * sc + 1.0f;
      acc.x = acc.x * sc + v0x;
      acc.y = acc.y * sc + v0y;
      m = sa;
    } else {
      float wgt = exp2f(d0);
      den += wgt;
      acc.x += wgt * v0x;
      acc.y += wgt * v0y;
    }
  }
  float inv = 1.f / (den + 1e-16f);
  ((float2*)(att + (size_t)wid * DIM))[lane] = make_float2(acc.x * inv, acc.y * inv);
}

// ---------- K5/K6b: out = LN((a+b)/2)*g + be (+ optional bf16 copy) ----------
__global__ __launch_bounds__(256) void add_ln_kernel(
    const float* __restrict__ a, const float* __restrict__ b,
    const float* __restrict__ g, const float* __restrict__ be,
    float* __restrict__ out, short* __restrict__ ybf, int nrows) {
  int wave = (blockIdx.x * 256 + threadIdx.x) >> 6;
  int lane = threadIdx.x & 63;
  if (wave >= nrows) return;
  float2 av = ((const float2*)a)[(size_t)wave * 64 + lane];
  float2 bv = ((const float2*)b)[(size_t)wave * 64 + lane];
  float y0 = (av.x + bv.x) * 0.5f, y1 = (av.y + bv.y) * 0.5f;
  float s = y0 + y1;
  #pragma unroll
  for (int off = 32; off; off >>= 1) s += __shfl_xor(s, off);
  float mean = s * (1.0f / 128.0f);
  float d0 = y0 - mean, d1 = y1 - mean;
  float v = d0 * d0 + d1 * d1;
  #pragma unroll
  for (int off = 32; off; off >>= 1) v += __shfl_xor(v, off);
  float rstd = 1.0f / sqrtf(v * (1.0f / 128.0f) + 1e-5f);
  float2 gv = ((const float2*)g)[lane];
  float2 bev = ((const float2*)be)[lane];
  float2 o;
  o.x = gv.x * d0 * rstd + bev.x;
  o.y = gv.y * d1 * rstd + bev.y;
  ((float2*)out)[(size_t)wave * 64 + lane] = o;
  if (ybf) {
    unsigned pk = (unsigned short)f2bf(o.x) | ((unsigned)(unsigned short)f2bf(o.y) << 16);
    ((unsigned*)ybf)[(size_t)wave * 64 + lane] = pk;
  }
}

// ---------- K6: bf16-MFMA fused FFN, block-shared B via double-buffered LDS ----
__global__ __launch_bounds__(256) void ffn_mfma_kernel(
    const short* __restrict__ Ybf, const short* __restrict__ W1F,
    const float* __restrict__ b1, const short* __restrict__ W2F,
    const float* __restrict__ b2, float* __restrict__ ff, int nrows) {
  __shared__ short Bsm[2][8192];     // 32KB: [buf][W1 chunk 4096 | W2 chunk 4096]
  __shared__ float Hlds[4][16 * 36]; // 9216B, per-wave H repack region
  const int tid = threadIdx.x;
  const int w = tid >> 6, lane = tid & 63;
  const int a = lane >> 4, c = lane & 15;
  const int rowbase = blockIdx.x * 64 + w * 16;
  float* Hw = Hlds[w];

  short8 af[4];
  {
    int r = rowbase + c;
    if (r < nrows) {
      const short* yp = Ybf + (size_t)r * 128 + a * 8;
      #pragma unroll
      for (int kc = 0; kc < 4; ++kc)
        af[kc] = *(const short8*)(yp + kc * 32);
    } else {
      short8 z = {0, 0, 0, 0, 0, 0, 0, 0};
      #pragma unroll
      for (int kc = 0; kc < 4; ++kc) af[kc] = z;
    }
  }

  {
    short8 t0 = *(const short8*)(W1F + tid * 8);
    short8 t1 = *(const short8*)(W1F + 2048 + tid * 8);
    short8 t2 = *(const short8*)(W2F + tid * 8);
    short8 t3 = *(const short8*)(W2F + 2048 + tid * 8);
    *(short8*)(&Bsm[0][tid * 8])        = t0;
    *(short8*)(&Bsm[0][2048 + tid * 8]) = t1;
    *(short8*)(&Bsm[0][4096 + tid * 8]) = t2;
    *(short8*)(&Bsm[0][6144 + tid * 8]) = t3;
  }
  __syncthreads();

  f32x4 acc2[8];
  #pragma unroll
  for (int i = 0; i < 8; ++i) acc2[i] = (f32x4){0.f, 0.f, 0.f, 0.f};

  int cb = 0;
  for (int hc = 0; hc < 16; ++hc) {
    short8 s0, s1, s2, s3;
    if (hc < 15) {
      const short* p1 = W1F + (hc + 1) * 4096;
      const short* p2 = W2F + (hc + 1) * 4096;
      s0 = *(const short8*)(p1 + tid * 8);
      s1 = *(const short8*)(p1 + 2048 + tid * 8);
      s2 = *(const short8*)(p2 + tid * 8);
      s3 = *(const short8*)(p2 + 2048 + tid * 8);
    }
    const short* B1 = &Bsm[cb][0];
    const short* B2 = &Bsm[cb][4096];
    f32x4 acc1[2];
    acc1[0] = (f32x4){0.f, 0.f, 0.f, 0.f};
    acc1[1] = (f32x4){0.f, 0.f, 0.f, 0.f};
    #pragma unroll
    for (int t = 0; t < 2; ++t) {
      #pragma unroll
      for (int kc = 0; kc < 4; ++kc) {
        short8 bfr = *(const short8*)(B1 + ((t * 4 + kc) << 9) + lane * 8);
        acc1[t] = __builtin_amdgcn_mfma_f32_16x16x32_bf16(af[kc], bfr, acc1[t], 0, 0, 0);
      }
    }
    #pragma unroll
    for (int t = 0; t < 2; ++t) {
      float b1v = b1[hc * 32 + t * 16 + c];
      #pragma unroll
      for (int r = 0; r < 4; ++r) {
        float hv = fmaxf(acc1[t][r] + b1v, 0.f);
        Hw[(4 * a + r) * 36 + t * 16 + c] = hv;
      }
    }
    asm volatile("s_waitcnt lgkmcnt(0)" ::: "memory");
    float4 h0 = *(const float4*)(Hw + c * 36 + a * 8);
    float4 h1 = *(const float4*)(Hw + c * 36 + a * 8 + 4);
    short8 a2;
    a2[0] = f2bf(h0.x); a2[1] = f2bf(h0.y); a2[2] = f2bf(h0.z); a2[3] = f2bf(h0.w);
    a2[4] = f2bf(h1.x); a2[5] = f2bf(h1.y); a2[6] = f2bf(h1.z); a2[7] = f2bf(h1.w);
    asm volatile("s_waitcnt lgkmcnt(0)" ::: "memory");
    #pragma unroll
    for (int nt = 0; nt < 8; ++nt) {
      short8 bfr = *(const short8*)(B2 + (nt << 9) + lane * 8);
      acc2[nt] = __builtin_amdgcn_mfma_f32_16x16x32_bf16(a2, bfr, acc2[nt], 0, 0, 0);
    }
    if (hc < 15) {
      int nb = cb ^ 1;
      *(short8*)(&Bsm[nb][tid * 8])        = s0;
      *(short8*)(&Bsm[nb][2048 + tid * 8]) = s1;
      *(short8*)(&Bsm[nb][4096 + tid * 8]) = s2;
      *(short8*)(&Bsm[nb][6144 + tid * 8]) = s3;
      __syncthreads();
      cb = nb;
    }
  }
  #pragma unroll
  for (int nt = 0; nt < 8; ++nt) {
    float b2v = b2[nt * 16 + c];
    #pragma unroll
    for (int r = 0; r < 4; ++r) {
      int row = rowbase + 4 * a + r;
      if (row < nrows)
        ff[(size_t)row * 128 + nt * 16 + c] = acc2[nt][r] + b2v;
    }
  }
}

// ---------- K8: in-place scale of output ----------
__global__ __launch_bounds__(256) void scale_kernel(float4* __restrict__ out,
                                                    const float* __restrict__ scl,
                                                    int n4) {
  int t = blockIdx.x * 256 + threadIdx.x;
  if (t < n4) {
    float s = scl[0];
    float4 v = out[t];
    v.x *= s; v.y *= s; v.z *= s; v.w *= s;
    out[t] = v;
  }
}

extern "C" void kernel_launch(void* const* d_in, const int* in_sizes, int n_in,
                              void* d_out, int out_size, void* d_ws, size_t ws_size,
                              hipStream_t stream) {
  const float* x   = (const float*)d_in[0];
  const int*   ei  = (const int*)  d_in[1];
  const float* Wq  = (const float*)d_in[2];
  const float* Wk  = (const float*)d_in[3];
  const float* Wv  = (const float*)d_in[4];
  const float* W1  = (const float*)d_in[5];
  const float* b1  = (const float*)d_in[6];
  const float* W2  = (const float*)d_in[7];
  const float* b2  = (const float*)d_in[8];
  const float* g1  = (const float*)d_in[9];
  const float* be1 = (const float*)d_in[10];
  const float* g2  = (const float*)d_in[11];
  const float* be2 = (const float*)d_in[12];
  float* out = (float*)d_out;
  float* ws  = (float*)d_ws;

  const size_t ND = (size_t)N_NODES * DIM;  // 6,400,000 floats
  const int NB = (N_NODES + 1023) / 1024;   // 49 scan blocks

  // ---- workspace layout (u32 units from ws base), total ~105.6 MB ----
  float* CR0    = ws;      // ws[0]
  float* SCL    = ws + 1;  // ws[1]
  int*   ROWPTR = (int*)(ws + 16);            // 50001 (+pad to 50016)
  int*   CUR    = (int*)(ws + 16 + 50016);    // 50000 (counts, then cursors)
  int*   ESORT  = CUR + 50000;                // 600000
  int*   LOC    = ESORT;                      // alias: dead before scatter writes
  int*   PART   = ESORT + 51200;              // 50 ints, still inside ESORT region
  short* W1F    = (short*)(ws + 700032);      // 65536 shorts (fragment-major)
  short* W2F    = W1F + 65536;                // 65536 shorts (fragment-major)
  short* WqF    = W2F + 65536;                // 16384 shorts (fragment-major)
  short* WkF    = WqF + 16384;                // 16384 shorts
  short* WvF    = WkF + 16384;                // 16384 shorts
  float* Q      = ws + 790144;                // 16B-aligned
  float* K      = Q + ND;                     // region reserved; holds Kb (bf16)
  float* V      = K + ND;                     // region reserved; holds Vb (bf16)
  float* ATT    = V + ND;
  short* Kbf    = (short*)K;
  short* Vbf    = (short*)V;
  short* YBF    = (short*)Q;  // alias: Q dead after attn_kernel
  float* Y      = K;          // alias: K region dead after attn_kernel
  float* FF     = V;          // alias: V region dead after attn_kernel

  // 0. weight transposes -> bf16 (tiny)
  convw_kernel<<<512, 256, 0, stream>>>(W1, W2, W1F, W2F);
  convqkv_kernel<<<192, 256, 0, stream>>>(Wq, Wk, Wv, WqF, WkF, WvF);
  // 1. cr0 from raw x rows 0..3
  cr_kernel<<<1, 128, 0, stream>>>(x, 0.0f, 0, nullptr, CR0);
  // 2. Q,K,V GEMMs — bf16 MFMA; K,V emitted as bf16; frag-major B loads
  qkv_mfma_kernel<<<(N_NODES + 63) / 64, 256, 0, stream>>>(x, WqF, WkF, WvF, Q, Kbf, Vbf, N_NODES);
  // 3. CSR build: histogram -> two-level scan -> scatter
  zero_int_kernel<<<(N_NODES + 255) / 256, 256, 0, stream>>>(CUR, N_NODES);
  count_kernel<<<(N_EDGES + 255) / 256, 256, 0, stream>>>(ei, CUR, N_EDGES);
  blockscan_kernel<<<NB, 1024, 0, stream>>>(CUR, LOC, PART, N_NODES);
  partscan_kernel<<<1, 64, 0, stream>>>(PART, NB);
  scanapply_kernel<<<NB, 1024, 0, stream>>>(LOC, PART, ROWPTR, CUR, N_NODES, NB);
  scatter_kernel<<<(N_EDGES + 255) / 256, 256, 0, stream>>>(ei, CUR, ESORT, N_EDGES);
  // 4. fused attention: defer-max online softmax, bf16 K/V gathers
  attn_kernel<<<N_NODES / 4, 256, 0, stream>>>(ROWPTR, ESORT, Q, Kbf, Vbf, ATT);
  // 5. y = LN1((x+att)/2)  (+ bf16 copy for FFN, into dead Q region)
  add_ln_kernel<<<N_NODES / 4, 256, 0, stream>>>(x, ATT, g1, be1, Y, YBF, N_NODES);
  // 6. ff = FFN(y)  — bf16 MFMA, LDS-staged B
  ffn_mfma_kernel<<<(N_NODES + 63) / 64, 256, 0, stream>>>(YBF, W1F, b1, W2F, b2, FF, N_NODES);
  // 7. z = LN2((y+ff)/2) -> d_out
  add_ln_kernel<<<N_NODES / 4, 256, 0, stream>>>(Y, FF, g2, be2, out, nullptr, N_NODES);
  // 8. cr on z, scale factor -> SCL
  cr_kernel<<<1, 128, 0, stream>>>(out, 1.0f, 1, CR0, SCL);
  // 9. out *= scale
  scale_kernel<<<(int)(ND / 4 / 256), 256, 0, stream>>>((float4*)out, SCL, (int)(ND / 4));
}